// Round 8
// baseline (484.607 us; speedup 1.0000x reference)
//
#include <hip/hip_runtime.h>
#include <math.h>

// ---------------- problem constants (fixed by setup_inputs) ----------------
constexpr int D   = 64;
constexpr int H   = 8;
constexpr int HD  = 8;
constexpr int NL  = 3;
constexpr int FFNx= 256;
constexpr int Bb  = 4;
constexpr int Ss  = 2048;
constexpr int NT  = Bb * Ss;        // 8192 tokens
constexpr int MAXC= 1024;
constexpr int MCL = 16;

// attention task decomposition: uniform tasks, chunk-major enumeration.
// Each task (128 queries x 128 keys) is computed by TWO waves (64 keys each)
// merged through LDS -> 8704 waves for latency hiding, same partial traffic.
constexpr int QW   = 128;            // queries per task (2 per lane)
constexpr int CH   = 128;            // keys per task
constexpr int TPB  = 136;            // tasks per (b,h): sum_{s=0..15} (16-s)
constexpr int BPB  = 68;             // blocks per (b,h) (2 tasks per block)
constexpr int PBSZ = 1152;           // floats per partial: l(128) + o(1024)

// ---------------- workspace layout (float elements) ----------------
constexpr size_t WX  = 0;                        // [NT*D] = 524288
constexpr size_t WQ  = 524288;                   // [NT*D] (U alias, needs NT*FFN)
constexpr size_t WKV = 2621440;                  // [32*2048*16] interleaved K|V
constexpr size_t WO  = 3670016;                  // [NT*D]
constexpr size_t WPB = 4194304;                  // [32*TPB*PBSZ] attn partials
constexpr size_t WU  = WQ;                       // [NT*FFN] aliases Q
constexpr size_t WL1 = 9764864;                  // [NT]
constexpr size_t WEM = WL1 + NT;                 // [NT] int
constexpr size_t WCP = WEM + NT;                 // [NT] int
constexpr size_t WCT = WCP + NT;                 // [Ss*4]
constexpr size_t WST = WCT + Ss*4;               // [Ss*4]  (end ~9.81M floats)

constexpr float LOG2E = 1.4426950408889634f;

typedef float v2f __attribute__((ext_vector_type(2)));

__device__ __forceinline__ float rdlane(float v, int l) {
    return __builtin_bit_cast(float, __builtin_amdgcn_readlane(__builtin_bit_cast(int, v), l));
}

// ---------------- init: copy x -> X, build rope tables ----------------
__global__ void k_init(const float* __restrict__ x, float* __restrict__ X,
                       float* __restrict__ ct, float* __restrict__ st) {
    int i = blockIdx.x * blockDim.x + threadIdx.x;
    constexpr int N4 = NT * D / 4;
    if (i < N4) ((float4*)X)[i] = ((const float4*)x)[i];
    if (i < Ss * 4) {
        int s = i >> 2, f = i & 3;
        const float fr[4] = {1.0f, 0.1f, 0.01f, 0.001f};
        float ang = (float)s * fr[f];
        ct[i] = cosf(ang);
        st[i] = sinf(ang);
    }
}

// ---------------- rmsnorm + QKV + rope (wave-per-token, readlane bcast) ----
__global__ __launch_bounds__(256) void k_qkv(
    const float* __restrict__ X, const float* __restrict__ Wq,
    const float* __restrict__ Wk, const float* __restrict__ Wv,
    const float* __restrict__ g1, const float* __restrict__ ct,
    const float* __restrict__ st, float* __restrict__ Q,
    float* __restrict__ KV) {
    __shared__ float wq_s[D*D], wk_s[D*D], wv_s[D*D];
    __shared__ float g_s[D];
    int tid = threadIdx.x;
    for (int i = tid; i < D*D; i += 256) {
        wq_s[i] = Wq[i]; wk_s[i] = Wk[i]; wv_s[i] = Wv[i];
    }
    if (tid < D) g_s[tid] = g1[tid];
    __syncthreads();
    int w = tid >> 6, d = tid & 63;
    int t0 = blockIdx.x * 32;
    for (int it = 0; it < 8; ++it) {
        int t = t0 + it*4 + w;
        float xv = X[t*D + d];
        float ss = xv * xv;
        #pragma unroll
        for (int off = 32; off; off >>= 1) ss += __shfl_xor(ss, off);
        float r = 1.0f / sqrtf(ss * (1.0f/D) + 1e-6f);
        float h = xv * g_s[d] * r;
        float aq = 0.f, ak = 0.f, av = 0.f;
        #pragma unroll
        for (int j = 0; j < D; ++j) {
            float hj = rdlane(h, j);
            aq += hj * wq_s[j*D + d];
            ak += hj * wk_s[j*D + d];
            av += hj * wv_s[j*D + d];
        }
        int s  = t & (Ss - 1);
        int e  = d & 7;
        int fi = e & 3;
        float c  = ct[s*4 + fi];
        float sn = st[s*4 + fi];
        float pq = __shfl_xor(aq, 4);
        float pk = __shfl_xor(ak, 4);
        float rq, rk;
        if (e < 4) { rq = aq*c - pq*sn; rk = ak*c - pk*sn; }
        else       { rq = pq*sn + aq*c; rk = pk*sn + ak*c; }
        Q[t*D + d] = rq;
        int bq = t >> 11;
        int hh = d >> 3;
        float* kvp = KV + ((((size_t)(bq*H + hh))*Ss + s) << 4);
        kvp[e]     = rk;
        kvp[8 + e] = av;
    }
}

// ---------------- fused attention inner loop: 64 keys, fixed-bias exp2 ----
template<bool DIAG>
__device__ __forceinline__ void attn_loop(
    const float4* __restrict__ kvb, int L, int rel0,
    const v2f* __restrict__ q01, v2f& l01, v2f* __restrict__ oP) {
    for (int j0 = 0; j0 < 64; j0 += 16) {
        v2f p01[16];
        #pragma unroll
        for (int jj = 0; jj < 16; ++jj) {
            int j = j0 + jj;
            const float4* kv = kvb + (size_t)j*4;
            float4 ka = kv[0];
            float4 kb = kv[1];
            v2f acc;
            acc  = q01[0] * (v2f){ka.x, ka.x};
            acc += q01[1] * (v2f){ka.y, ka.y};
            acc += q01[2] * (v2f){ka.z, ka.z};
            acc += q01[3] * (v2f){ka.w, ka.w};
            acc += q01[4] * (v2f){kb.x, kb.x};
            acc += q01[5] * (v2f){kb.y, kb.y};
            acc += q01[6] * (v2f){kb.z, kb.z};
            acc += q01[7] * (v2f){kb.w, kb.w};
            if (DIAG) {
                int rel = rel0 + j;
                if (rel > L)      acc.x = -1e30f;
                if (rel > L + 64) acc.y = -1e30f;
            }
            p01[jj].x = exp2f(acc.x);
            p01[jj].y = exp2f(acc.y);
        }
        #pragma unroll
        for (int jj = 0; jj < 16; ++jj) {
            int j = j0 + jj;
            const float4* kv = kvb + (size_t)j*4;
            float4 va = kv[2];
            float4 vb = kv[3];
            v2f p = p01[jj];
            l01 += p;
            oP[0] += p * (v2f){va.x, va.x};
            oP[1] += p * (v2f){va.y, va.y};
            oP[2] += p * (v2f){va.z, va.z};
            oP[3] += p * (v2f){va.w, va.w};
            oP[4] += p * (v2f){vb.x, vb.x};
            oP[5] += p * (v2f){vb.y, vb.y};
            oP[6] += p * (v2f){vb.z, vb.z};
            oP[7] += p * (v2f){vb.w, vb.w};
        }
    }
}

// ---------------- causal attention: paired-wave split-K, XCD-pinned -------
// blockIdx = xcd + 8*slot; bh = (slot/BPB)*8 + xcd (all blocks of a bh on
// one XCD -> 128KB KV stays L2-resident). Block = 4 waves = 2 tasks; wave
// pair {2p, 2p+1} computes task blk*2+p over key-halves 0/1 and merges via
// LDS; even wave writes the combined partial (layout/traffic unchanged).
__global__ __launch_bounds__(256) void k_attn2(
    const float* __restrict__ Qg, const float* __restrict__ KV,
    float* __restrict__ PB) {
    __shared__ float comb[2][PBSZ];
    int xcd  = blockIdx.x & 7;
    int slot = blockIdx.x >> 3;
    int bhg  = slot / BPB;
    int blk  = slot - bhg * BPB;
    int bh   = bhg * 8 + xcd;
    int wv   = threadIdx.x >> 6;
    int pair = wv >> 1;
    int half = wv & 1;
    int widb = blk * 2 + pair;                 // task 0..135 within bh
    int L = threadIdx.x & 63;
    int rem = widb;
    int s = 0;
    while (rem >= 16 - s) { rem -= 16 - s; ++s; }
    int t = s + rem;
    int b = bh >> 3, h = bh & 7;
    int qmin = t * QW;
    int k0 = s * CH + half * 64;

    const float SC = 0.35355339059327373f * LOG2E;   // 1/sqrt(8) * log2(e)
    const float* qp = Qg + ((size_t)(b*Ss + qmin + L))*D + h*HD;
    float4 qa0 = *(const float4*)(qp);
    float4 qb0 = *(const float4*)(qp + 4);
    float4 qa1 = *(const float4*)(qp + 64*D);
    float4 qb1 = *(const float4*)(qp + 64*D + 4);
    v2f q01[8];
    q01[0] = (v2f){qa0.x*SC, qa1.x*SC};
    q01[1] = (v2f){qa0.y*SC, qa1.y*SC};
    q01[2] = (v2f){qa0.z*SC, qa1.z*SC};
    q01[3] = (v2f){qa0.w*SC, qa1.w*SC};
    q01[4] = (v2f){qb0.x*SC, qb1.x*SC};
    q01[5] = (v2f){qb0.y*SC, qb1.y*SC};
    q01[6] = (v2f){qb0.z*SC, qb1.z*SC};
    q01[7] = (v2f){qb0.w*SC, qb1.w*SC};

    v2f l01 = (v2f){0.f, 0.f};
    v2f oP[8];
    #pragma unroll
    for (int e = 0; e < 8; ++e) oP[e] = (v2f){0.f, 0.f};

    const float4* kvb = (const float4*)(KV + (((size_t)bh*Ss + k0) << 4));
    if (s == t) attn_loop<true >(kvb, L, half*64, q01, l01, oP);
    else        attn_loop<false>(kvb, L, half*64, q01, l01, oP);

    if (half == 1) {
        comb[pair][L]      = l01.x;
        comb[pair][64 + L] = l01.y;
        #pragma unroll
        for (int e = 0; e < 8; ++e) {
            comb[pair][128 + e*128 + L]      = oP[e].x;
            comb[pair][128 + e*128 + 64 + L] = oP[e].y;
        }
    }
    __syncthreads();
    if (half == 0) {
        float* pb = PB + ((size_t)bh * TPB + widb) * PBSZ;
        pb[L]      = l01.x + comb[pair][L];
        pb[64 + L] = l01.y + comb[pair][64 + L];
        #pragma unroll
        for (int e = 0; e < 8; ++e) {
            pb[128 + e*128 + L]      = oP[e].x + comb[pair][128 + e*128 + L];
            pb[128 + e*128 + 64 + L] = oP[e].y + comb[pair][128 + e*128 + 64 + L];
        }
    }
}

// ---------------- combine partials -> O (plain sums, fixed bias) ----------
__global__ __launch_bounds__(128) void k_comb(const float* __restrict__ PB,
                                              float* __restrict__ Og) {
    int qs = threadIdx.x;           // 0..127
    int t  = blockIdx.x & 15;
    int bh = blockIdx.x >> 4;
    int b = bh >> 3, h = bh & 7;
    float Lx = 0.f;
    float O[8] = {0,0,0,0,0,0,0,0};
    for (int s3 = 0; s3 <= t; ++s3) {
        int idx = 16*s3 - (s3*(s3-1))/2 + (t - s3);
        const float* pb = PB + (size_t)(bh*TPB + idx) * PBSZ;
        Lx += pb[qs];
        #pragma unroll
        for (int e = 0; e < 8; ++e) O[e] += pb[128 + e*128 + qs];
    }
    float inv = 1.0f / Lx;
    float* op = Og + ((size_t)(b*Ss + t*QW + qs))*D + h*HD;
    #pragma unroll
    for (int e = 0; e < 8; ++e) op[e] = O[e] * inv;
}

// ---------------- x += O @ Wo (readlane bcast) ----------------
__global__ __launch_bounds__(256) void k_post1(
    float* __restrict__ X, const float* __restrict__ Og,
    const float* __restrict__ Wo) {
    __shared__ float ws_[D*D];
    int tid = threadIdx.x;
    for (int i = tid; i < D*D; i += 256) ws_[i] = Wo[i];
    __syncthreads();
    int w = tid >> 6, d = tid & 63;
    int t0 = blockIdx.x * 32;
    for (int it = 0; it < 8; ++it) {
        int t = t0 + it*4 + w;
        float ov = Og[t*D + d];
        float a = 0.f;
        #pragma unroll
        for (int j = 0; j < D; ++j) a += rdlane(ov, j) * ws_[j*D + d];
        X[t*D + d] += a;
    }
}

// ---------------- rms2 + W1 + gelu -> U (transposed LDS, packed f32) ------
__global__ __launch_bounds__(256) void k_ffn1(
    const float* __restrict__ X, const float* __restrict__ g2,
    const float* __restrict__ W1, float* __restrict__ U) {
    __shared__ __align__(16) float h2t[64][20];   // [dim][token], 80B rows
    __shared__ float part[16][16];
    __shared__ float g_s[D];
    int tid = threadIdx.x;
    if (tid < D) g_s[tid] = g2[tid];
    int t0 = blockIdx.x * 16;
    int tk = tid >> 4, li = tid & 15;
    float x0 = X[(t0+tk)*D + li];
    float x1 = X[(t0+tk)*D + li + 16];
    float x2 = X[(t0+tk)*D + li + 32];
    float x3 = X[(t0+tk)*D + li + 48];
    part[tk][li] = x0*x0 + x1*x1 + x2*x2 + x3*x3;
    __syncthreads();
    if (tid < 16) {
        float s = 0.f;
        #pragma unroll
        for (int i = 0; i < 16; ++i) s += part[tid][i];
        part[tid][0] = 1.0f / sqrtf(s * (1.0f/D) + 1e-6f);
    }
    __syncthreads();
    float r = part[tk][0];
    h2t[li][tk]      = x0 * g_s[li]      * r;
    h2t[li + 16][tk] = x1 * g_s[li + 16] * r;
    h2t[li + 32][tk] = x2 * g_s[li + 32] * r;
    h2t[li + 48][tk] = x3 * g_s[li + 48] * r;
    __syncthreads();
    int f = tid;
    v2f acc2[8];
    #pragma unroll
    for (int i = 0; i < 8; ++i) acc2[i] = (v2f){0.f, 0.f};
    for (int j = 0; j < D; ++j) {
        float wv = W1[j*FFNx + f];
        v2f wv2 = (v2f){wv, wv};
        const float4* hp = (const float4*)&h2t[j][0];
        float4 a0 = hp[0], a1 = hp[1], a2 = hp[2], a3 = hp[3];
        const v2f* a0v = (const v2f*)&a0;
        const v2f* a1v = (const v2f*)&a1;
        const v2f* a2v = (const v2f*)&a2;
        const v2f* a3v = (const v2f*)&a3;
        acc2[0] += a0v[0]*wv2;  acc2[1] += a0v[1]*wv2;
        acc2[2] += a1v[0]*wv2;  acc2[3] += a1v[1]*wv2;
        acc2[4] += a2v[0]*wv2;  acc2[5] += a2v[1]*wv2;
        acc2[6] += a3v[0]*wv2;  acc2[7] += a3v[1]*wv2;
    }
    #pragma unroll
    for (int i = 0; i < 8; ++i) {
        float ua = acc2[i].x;
        float ub = acc2[i].y;
        ua = 0.5f * ua * (1.0f + erff(ua * 0.70710678118654752f));
        ub = 0.5f * ub * (1.0f + erff(ub * 0.70710678118654752f));
        U[(t0 + 2*i)*FFNx + f]     = ua;
        U[(t0 + 2*i + 1)*FFNx + f] = ub;
    }
}

// ---------------- x += U @ W2 (transposed LDS, packed f32) ----------------
__global__ __launch_bounds__(256) void k_ffn2(
    float* __restrict__ X, const float* __restrict__ U,
    const float* __restrict__ W2) {
    __shared__ __align__(16) float ult[FFNx][20];  // [f][token]
    __shared__ float red[4][16][D];
    int tid = threadIdx.x;
    int t0 = blockIdx.x * 16;
    #pragma unroll
    for (int k = 0; k < 16; ++k) ult[tid][k] = U[(t0 + k)*FFNx + tid];
    __syncthreads();
    int d = tid & 63, fp = tid >> 6;
    v2f acc2[8];
    #pragma unroll
    for (int i = 0; i < 8; ++i) acc2[i] = (v2f){0.f, 0.f};
    for (int fo = 0; fo < 64; ++fo) {
        int f = fp*64 + fo;
        float wv = W2[f*D + d];
        v2f wv2 = (v2f){wv, wv};
        const float4* up = (const float4*)&ult[f][0];
        float4 u0 = up[0], u1 = up[1], u2 = up[2], u3 = up[3];
        const v2f* u0v = (const v2f*)&u0;
        const v2f* u1v = (const v2f*)&u1;
        const v2f* u2v = (const v2f*)&u2;
        const v2f* u3v = (const v2f*)&u3;
        acc2[0] += u0v[0]*wv2;  acc2[1] += u0v[1]*wv2;
        acc2[2] += u1v[0]*wv2;  acc2[3] += u1v[1]*wv2;
        acc2[4] += u2v[0]*wv2;  acc2[5] += u2v[1]*wv2;
        acc2[6] += u3v[0]*wv2;  acc2[7] += u3v[1]*wv2;
    }
    #pragma unroll
    for (int i = 0; i < 8; ++i) {
        red[fp][2*i][d]     = acc2[i].x;
        red[fp][2*i + 1][d] = acc2[i].y;
    }
    __syncthreads();
    int tk = tid >> 6;
    #pragma unroll
    for (int k = 0; k < 4; ++k) {
        int tt = tk + k*4;
        float sum = red[0][tt][d] + red[1][tt][d] + red[2][tt][d] + red[3][tt][d];
        X[(t0 + tt)*D + d] += sum;
    }
}

// ---------------- head ----------------
__global__ __launch_bounds__(256) void k_head(
    const float* __restrict__ X, const float* __restrict__ Wh,
    const float* __restrict__ bh, float* __restrict__ logit1,
    int* __restrict__ em) {
    int tid = threadIdx.x;
    int w = tid >> 6, d = tid & 63;
    int t = blockIdx.x*4 + w;
    float xv = X[t*D + d];
    float p0 = xv * Wh[d*2];
    float p1 = xv * Wh[d*2 + 1];
    #pragma unroll
    for (int off = 32; off; off >>= 1) {
        p0 += __shfl_xor(p0, off);
        p1 += __shfl_xor(p1, off);
    }
    if (d == 0) {
        float l0 = p0 + bh[0], l1 = p1 + bh[1];
        em[t] = (l0 > l1) ? 1 : 0;
        logit1[t] = l1;
    }
}

// ---------------- reg term ----------------
__global__ void k_reg(const float* __restrict__ logit1, float* __restrict__ outreg) {
    __shared__ float red[256];
    int tid = threadIdx.x;
    float s = 0.f;
    for (int i = tid; i < NT; i += 256) s += logit1[i];
    red[tid] = s;
    __syncthreads();
    for (int off = 128; off; off >>= 1) {
        if (tid < off) red[tid] += red[tid + off];
        __syncthreads();
    }
    if (tid == 0) *outreg = red[0] * (1.0f / NT);
}

// ---------------- per-batch scan ----------------
__global__ __launch_bounds__(256) void k_scan(const int* __restrict__ em,
                                              int* __restrict__ cp) {
    __shared__ int ssum[256], smax[256];
    __shared__ int sany, stot;
    int b = blockIdx.x, tid = threadIdx.x;
    const int* e = em + b*Ss;
    int base = tid * 8;
    int loc[8];
    int lsum = 0, lor = 0;
    #pragma unroll
    for (int i = 0; i < 8; ++i) { loc[i] = e[base + i]; lsum += loc[i]; lor |= loc[i]; }
    ssum[tid] = lor;
    __syncthreads();
    if (tid == 0) { int a = 0; for (int i = 0; i < 256; ++i) a |= ssum[i]; sany = a; }
    __syncthreads();
    int any = sany;
    __syncthreads();
    if (!any && tid == 255) { loc[7] = 1; lsum = 1; }
    int prev = (tid == 0) ? 1 : e[base - 1];
    if (!any && tid) prev = 0;
    int mk[8];
    int lmax = -1;
    #pragma unroll
    for (int i = 0; i < 8; ++i) {
        int pe = (i == 0) ? prev : loc[i - 1];
        if (i == 7 && !any && tid == 255) pe = e[base + 6];
        mk[i] = pe ? (base + i) : -1;
        lmax = max(lmax, mk[i]);
    }
    ssum[tid] = lsum; smax[tid] = lmax;
    __syncthreads();
    if (tid == 0) {
        int rs = 0, rm = -1;
        for (int i = 0; i < 256; ++i) {
            int ts = ssum[i], tm = smax[i];
            ssum[i] = rs; smax[i] = rm;
            rs += ts; rm = max(rm, tm);
        }
        stot = rs;
    }
    __syncthreads();
    int run = ssum[tid], rmax = smax[tid], tot = stot;
    int* cpb = cp + b*Ss;
    #pragma unroll
    for (int i = 0; i < 8; ++i) {
        int s = base + i;
        rmax = max(rmax, mk[i]);
        int chunk = run;
        run += loc[i];
        int pos = s - rmax;
        bool valid = (chunk < tot) && (chunk < MAXC) && (pos < MCL);
        cpb[s] = valid ? (chunk * MCL + pos) : -1;
    }
}

// ---------------- fill / scatter ----------------
__global__ void k_fill(float* __restrict__ out, const float* __restrict__ pad,
                       const int* __restrict__ padid) {
    int i = blockIdx.x * blockDim.x + threadIdx.x;
    constexpr int N4  = Bb * MAXC * MCL * D / 4;
    constexpr int NI4 = Bb * MAXC * MCL / 4;
    if (i < N4) {
        ((float4*)out)[i] = ((const float4*)pad)[i & 15];
    } else if (i < N4 + NI4) {
        float pv = (float)(*padid);
        float4 v; v.x = pv; v.y = pv; v.z = pv; v.w = pv;
        ((float4*)out)[i] = v;
    }
}

__global__ __launch_bounds__(256) void k_scatter(
    const float* __restrict__ X, const int* __restrict__ cp,
    const int* __restrict__ ids, float* __restrict__ out) {
    int tid = threadIdx.x;
    int w = tid >> 6, d = tid & 63;
    int t = blockIdx.x*4 + w;
    int c = cp[t];
    if (c < 0) return;
    int b = t >> 11;
    float* dst = out + ((size_t)(b * MAXC * MCL) + c) * D;
    dst[d] = X[t*D + d];
    if (d == 0)
        out[(size_t)Bb*MAXC*MCL*D + (size_t)b*MAXC*MCL + c] = (float)ids[t];
}

// ---------------- launch ----------------
extern "C" void kernel_launch(void* const* d_in, const int* in_sizes, int n_in,
                              void* d_out, int out_size, void* d_ws, size_t ws_size,
                              hipStream_t stream) {
    const float* x    = (const float*)d_in[0];
    const float* pad  = (const float*)d_in[1];
    const int*   xids = (const int*)  d_in[2];
    const int*   padid= (const int*)  d_in[3];
    const float* Wq   = (const float*)d_in[4];
    const float* Wk   = (const float*)d_in[5];
    const float* Wv   = (const float*)d_in[6];
    const float* Wo   = (const float*)d_in[7];
    const float* ln1  = (const float*)d_in[8];
    const float* ln2  = (const float*)d_in[9];
    const float* W1   = (const float*)d_in[10];
    const float* W2   = (const float*)d_in[11];
    const float* Wh   = (const float*)d_in[12];
    const float* bh   = (const float*)d_in[13];
    float* out = (float*)d_out;
    float* ws  = (float*)d_ws;

    float* X  = ws + WX;
    float* Qb = ws + WQ;
    float* KVb= ws + WKV;
    float* Ob = ws + WO;
    float* PBb= ws + WPB;
    float* Ub = ws + WU;
    float* L1b= ws + WL1;
    int*   EMb= (int*)(ws + WEM);
    int*   CPb= (int*)(ws + WCP);
    float* ct = ws + WCT;
    float* st = ws + WST;

    k_init<<<2048, 256, 0, stream>>>(x, X, ct, st);
    for (int l = 0; l < NL; ++l) {
        k_qkv <<<256, 256, 0, stream>>>(X, Wq + l*D*D, Wk + l*D*D, Wv + l*D*D,
                                        ln1 + l*D, ct, st, Qb, KVb);
        k_attn2<<<32*BPB, 256, 0, stream>>>(Qb, KVb, PBb);
        k_comb <<<32*16, 128, 0, stream>>>(PBb, Ob);
        k_post1<<<256, 256, 0, stream>>>(X, Ob, Wo + l*D*D);
        k_ffn1<<<NT/16, 256, 0, stream>>>(X, ln2 + l*D, W1 + l*D*FFNx, Ub);
        k_ffn2<<<NT/16, 256, 0, stream>>>(X, Ub, W2 + l*FFNx*D);
    }
    k_head<<<NT/4, 256, 0, stream>>>(X, Wh, bh, L1b, EMb);
    k_reg <<<1, 256, 0, stream>>>(L1b, out + (size_t)Bb*MAXC*MCL*D + Bb*MAXC*MCL);
    k_scan<<<Bb, 256, 0, stream>>>(EMb, CPb);
    k_fill<<<(Bb*MAXC*MCL*D/4 + Bb*MAXC*MCL/4 + 255)/256, 256, 0, stream>>>(out, pad, padid);
    k_scatter<<<NT/4, 256, 0, stream>>>(X, CPb, xids, out);
}

// Round 9
// 416.723 us; speedup vs baseline: 1.1629x; 1.1629x over previous
//
#include <hip/hip_runtime.h>
#include <math.h>

// ---------------- problem constants (fixed by setup_inputs) ----------------
constexpr int D   = 64;
constexpr int H   = 8;
constexpr int HD  = 8;
constexpr int NL  = 3;
constexpr int FFNx= 256;
constexpr int Bb  = 4;
constexpr int Ss  = 2048;
constexpr int NT  = Bb * Ss;        // 8192 tokens
constexpr int MAXC= 1024;
constexpr int MCL = 16;

// attention task decomposition: uniform tasks, chunk-major enumeration
constexpr int QW   = 128;            // queries per wave (2 per lane)
constexpr int CH   = 128;            // keys per chunk task (== QW -> uniform)
constexpr int TPB  = 136;            // tasks per (b,h): sum_{s=0..15} (16-s)
constexpr int BPB  = 34;             // blocks per (b,h) (4 waves each)
constexpr int PBSZ = 1152;           // floats per partial: l(128) + o(1024)

// ---------------- workspace layout (float elements) ----------------
constexpr size_t WX  = 0;                        // [NT*D] = 524288
constexpr size_t WQ  = 524288;                   // [NT*D] (U alias, needs NT*FFN)
constexpr size_t WKV = 2621440;                  // [32*2048*16] interleaved K|V
constexpr size_t WO  = 3670016;                  // [NT*D]
constexpr size_t WPB = 4194304;                  // [32*TPB*PBSZ] attn partials
constexpr size_t WU  = WQ;                       // [NT*FFN] aliases Q
constexpr size_t WL1 = 9764864;                  // [NT]
constexpr size_t WEM = WL1 + NT;                 // [NT] int
constexpr size_t WCP = WEM + NT;                 // [NT] int
constexpr size_t WCT = WCP + NT;                 // [Ss*4]
constexpr size_t WST = WCT + Ss*4;               // [Ss*4]  (end ~9.81M floats)

constexpr float LOG2E = 1.4426950408889634f;

typedef float v2f __attribute__((ext_vector_type(2)));

__device__ __forceinline__ float rdlane(float v, int l) {
    return __builtin_bit_cast(float, __builtin_amdgcn_readlane(__builtin_bit_cast(int, v), l));
}

// ---------------- init: copy x -> X, build rope tables ----------------
__global__ void k_init(const float* __restrict__ x, float* __restrict__ X,
                       float* __restrict__ ct, float* __restrict__ st) {
    int i = blockIdx.x * blockDim.x + threadIdx.x;
    constexpr int N4 = NT * D / 4;
    if (i < N4) ((float4*)X)[i] = ((const float4*)x)[i];
    if (i < Ss * 4) {
        int s = i >> 2, f = i & 3;
        const float fr[4] = {1.0f, 0.1f, 0.01f, 0.001f};
        float ang = (float)s * fr[f];
        ct[i] = cosf(ang);
        st[i] = sinf(ang);
    }
}

// ---------------- rmsnorm + QKV + rope (wave-per-token, readlane bcast) ----
__global__ __launch_bounds__(256) void k_qkv(
    const float* __restrict__ X, const float* __restrict__ Wq,
    const float* __restrict__ Wk, const float* __restrict__ Wv,
    const float* __restrict__ g1, const float* __restrict__ ct,
    const float* __restrict__ st, float* __restrict__ Q,
    float* __restrict__ KV) {
    __shared__ float wq_s[D*D], wk_s[D*D], wv_s[D*D];
    __shared__ float g_s[D];
    int tid = threadIdx.x;
    for (int i = tid; i < D*D; i += 256) {
        wq_s[i] = Wq[i]; wk_s[i] = Wk[i]; wv_s[i] = Wv[i];
    }
    if (tid < D) g_s[tid] = g1[tid];
    __syncthreads();
    int w = tid >> 6, d = tid & 63;
    int t0 = blockIdx.x * 32;
    for (int it = 0; it < 8; ++it) {
        int t = t0 + it*4 + w;
        float xv = X[t*D + d];
        float ss = xv * xv;
        #pragma unroll
        for (int off = 32; off; off >>= 1) ss += __shfl_xor(ss, off);
        float r = 1.0f / sqrtf(ss * (1.0f/D) + 1e-6f);
        float h = xv * g_s[d] * r;
        float aq = 0.f, ak = 0.f, av = 0.f;
        #pragma unroll
        for (int j = 0; j < D; ++j) {
            float hj = rdlane(h, j);
            aq += hj * wq_s[j*D + d];
            ak += hj * wk_s[j*D + d];
            av += hj * wv_s[j*D + d];
        }
        int s  = t & (Ss - 1);
        int e  = d & 7;
        int fi = e & 3;
        float c  = ct[s*4 + fi];
        float sn = st[s*4 + fi];
        float pq = __shfl_xor(aq, 4);
        float pk = __shfl_xor(ak, 4);
        float rq, rk;
        if (e < 4) { rq = aq*c - pq*sn; rk = ak*c - pk*sn; }
        else       { rq = pq*sn + aq*c; rk = pk*sn + ak*c; }
        Q[t*D + d] = rq;
        int bq = t >> 11;
        int hh = d >> 3;
        float* kvp = KV + ((((size_t)(bq*H + hh))*Ss + s) << 4);
        kvp[e]     = rk;
        kvp[8 + e] = av;
    }
}

// ---------------- attention 64-key tile: KV in registers, readlane bcast --
// Lane j holds key j of the tile; key j is broadcast to all lanes via
// v_readlane (SGPR result), so the inner loop has ZERO memory operations.
template<bool DIAG>
__device__ __forceinline__ void attn_tile(
    float4 ka, float4 kb, float4 va, float4 vb,
    int L, int rel0, const v2f* __restrict__ q01,
    v2f& l01, v2f* __restrict__ oP) {
    #pragma unroll 8
    for (int j = 0; j < 64; ++j) {
        float k0 = rdlane(ka.x, j), k1 = rdlane(ka.y, j);
        float k2 = rdlane(ka.z, j), k3 = rdlane(ka.w, j);
        float k4 = rdlane(kb.x, j), k5 = rdlane(kb.y, j);
        float k6 = rdlane(kb.z, j), k7 = rdlane(kb.w, j);
        v2f acc;
        acc  = q01[0] * (v2f){k0, k0};
        acc += q01[1] * (v2f){k1, k1};
        acc += q01[2] * (v2f){k2, k2};
        acc += q01[3] * (v2f){k3, k3};
        acc += q01[4] * (v2f){k4, k4};
        acc += q01[5] * (v2f){k5, k5};
        acc += q01[6] * (v2f){k6, k6};
        acc += q01[7] * (v2f){k7, k7};
        if (DIAG) {
            int rel = rel0 + j;
            if (rel > L)      acc.x = -1e30f;
            if (rel > L + 64) acc.y = -1e30f;
        }
        v2f p;
        p.x = exp2f(acc.x);
        p.y = exp2f(acc.y);
        l01 += p;
        float v0 = rdlane(va.x, j), v1 = rdlane(va.y, j);
        float v2 = rdlane(va.z, j), v3 = rdlane(va.w, j);
        float v4 = rdlane(vb.x, j), v5 = rdlane(vb.y, j);
        float v6 = rdlane(vb.z, j), v7 = rdlane(vb.w, j);
        oP[0] += p * (v2f){v0, v0};
        oP[1] += p * (v2f){v1, v1};
        oP[2] += p * (v2f){v2, v2};
        oP[3] += p * (v2f){v3, v3};
        oP[4] += p * (v2f){v4, v4};
        oP[5] += p * (v2f){v5, v5};
        oP[6] += p * (v2f){v6, v6};
        oP[7] += p * (v2f){v7, v7};
    }
}

// ---------------- causal attention: reg-resident KV, XCD-pinned -----------
// blockIdx = xcd + 8*slot; bh = (slot/BPB)*8 + xcd (all 34 blocks of a bh
// on one XCD -> its 128KB KV stays L2-resident). All 12 VMEM loads (Q + two
// 64-key KV tiles, per-lane coalesced) issue up front; the key loop is pure
// VALU. Summation order over keys is sequential 0..127 (same as before).
__global__ __launch_bounds__(256) void k_attn2(
    const float* __restrict__ Qg, const float* __restrict__ KV,
    float* __restrict__ PB) {
    int xcd  = blockIdx.x & 7;
    int slot = blockIdx.x >> 3;
    int bhg  = slot / BPB;
    int blk  = slot - bhg * BPB;
    int bh   = bhg * 8 + xcd;
    int widb = blk * 4 + (threadIdx.x >> 6);   // task 0..135 within bh
    int L = threadIdx.x & 63;
    int rem = widb;
    int s = 0;
    while (rem >= 16 - s) { rem -= 16 - s; ++s; }
    int t = s + rem;
    int b = bh >> 3, h = bh & 7;
    int qmin = t * QW;
    int k0 = s * CH;

    // per-lane KV loads: lane L owns keys k0+L and k0+64+L (coalesced)
    const float4* kvL0 = (const float4*)(KV + (((size_t)bh*Ss + k0 + L) << 4));
    const float4* kvL1 = kvL0 + 64*4;
    float4 ka0 = kvL0[0], kb0 = kvL0[1], va0 = kvL0[2], vb0 = kvL0[3];
    float4 ka1 = kvL1[0], kb1 = kvL1[1], va1 = kvL1[2], vb1 = kvL1[3];

    const float SC = 0.35355339059327373f * LOG2E;   // 1/sqrt(8) * log2(e)
    const float* qp = Qg + ((size_t)(b*Ss + qmin + L))*D + h*HD;
    float4 qa0 = *(const float4*)(qp);
    float4 qb0 = *(const float4*)(qp + 4);
    float4 qa1 = *(const float4*)(qp + 64*D);
    float4 qb1 = *(const float4*)(qp + 64*D + 4);
    v2f q01[8];
    q01[0] = (v2f){qa0.x*SC, qa1.x*SC};
    q01[1] = (v2f){qa0.y*SC, qa1.y*SC};
    q01[2] = (v2f){qa0.z*SC, qa1.z*SC};
    q01[3] = (v2f){qa0.w*SC, qa1.w*SC};
    q01[4] = (v2f){qb0.x*SC, qb1.x*SC};
    q01[5] = (v2f){qb0.y*SC, qb1.y*SC};
    q01[6] = (v2f){qb0.z*SC, qb1.z*SC};
    q01[7] = (v2f){qb0.w*SC, qb1.w*SC};

    v2f l01 = (v2f){0.f, 0.f};
    v2f oP[8];
    #pragma unroll
    for (int e = 0; e < 8; ++e) oP[e] = (v2f){0.f, 0.f};

    if (s == t) {
        attn_tile<true >(ka0, kb0, va0, vb0, L, 0,  q01, l01, oP);
        attn_tile<true >(ka1, kb1, va1, vb1, L, 64, q01, l01, oP);
    } else {
        attn_tile<false>(ka0, kb0, va0, vb0, L, 0,  q01, l01, oP);
        attn_tile<false>(ka1, kb1, va1, vb1, L, 64, q01, l01, oP);
    }

    float* pb = PB + ((size_t)bh * TPB + widb) * PBSZ;
    pb[L]      = l01.x;
    pb[64 + L] = l01.y;
    #pragma unroll
    for (int e = 0; e < 8; ++e) {
        pb[128 + e*128 + L]      = oP[e].x;
        pb[128 + e*128 + 64 + L] = oP[e].y;
    }
}

// ---------------- combine partials -> O (plain sums, fixed bias) ----------
__global__ __launch_bounds__(128) void k_comb(const float* __restrict__ PB,
                                              float* __restrict__ Og) {
    int qs = threadIdx.x;           // 0..127
    int t  = blockIdx.x & 15;
    int bh = blockIdx.x >> 4;
    int b = bh >> 3, h = bh & 7;
    float Lx = 0.f;
    float O[8] = {0,0,0,0,0,0,0,0};
    for (int s3 = 0; s3 <= t; ++s3) {
        int idx = 16*s3 - (s3*(s3-1))/2 + (t - s3);
        const float* pb = PB + (size_t)(bh*TPB + idx) * PBSZ;
        Lx += pb[qs];
        #pragma unroll
        for (int e = 0; e < 8; ++e) O[e] += pb[128 + e*128 + qs];
    }
    float inv = 1.0f / Lx;
    float* op = Og + ((size_t)(b*Ss + t*QW + qs))*D + h*HD;
    #pragma unroll
    for (int e = 0; e < 8; ++e) op[e] = O[e] * inv;
}

// ---------------- x += O @ Wo (readlane bcast) ----------------
__global__ __launch_bounds__(256) void k_post1(
    float* __restrict__ X, const float* __restrict__ Og,
    const float* __restrict__ Wo) {
    __shared__ float ws_[D*D];
    int tid = threadIdx.x;
    for (int i = tid; i < D*D; i += 256) ws_[i] = Wo[i];
    __syncthreads();
    int w = tid >> 6, d = tid & 63;
    int t0 = blockIdx.x * 32;
    for (int it = 0; it < 8; ++it) {
        int t = t0 + it*4 + w;
        float ov = Og[t*D + d];
        float a = 0.f;
        #pragma unroll
        for (int j = 0; j < D; ++j) a += rdlane(ov, j) * ws_[j*D + d];
        X[t*D + d] += a;
    }
}

// ---------------- rms2 + W1 + gelu -> U (transposed LDS, packed f32) ------
__global__ __launch_bounds__(256) void k_ffn1(
    const float* __restrict__ X, const float* __restrict__ g2,
    const float* __restrict__ W1, float* __restrict__ U) {
    __shared__ __align__(16) float h2t[64][20];   // [dim][token], 80B rows
    __shared__ float part[16][16];
    __shared__ float g_s[D];
    int tid = threadIdx.x;
    if (tid < D) g_s[tid] = g2[tid];
    int t0 = blockIdx.x * 16;
    int tk = tid >> 4, li = tid & 15;
    float x0 = X[(t0+tk)*D + li];
    float x1 = X[(t0+tk)*D + li + 16];
    float x2 = X[(t0+tk)*D + li + 32];
    float x3 = X[(t0+tk)*D + li + 48];
    part[tk][li] = x0*x0 + x1*x1 + x2*x2 + x3*x3;
    __syncthreads();
    if (tid < 16) {
        float s = 0.f;
        #pragma unroll
        for (int i = 0; i < 16; ++i) s += part[tid][i];
        part[tid][0] = 1.0f / sqrtf(s * (1.0f/D) + 1e-6f);
    }
    __syncthreads();
    float r = part[tk][0];
    h2t[li][tk]      = x0 * g_s[li]      * r;
    h2t[li + 16][tk] = x1 * g_s[li + 16] * r;
    h2t[li + 32][tk] = x2 * g_s[li + 32] * r;
    h2t[li + 48][tk] = x3 * g_s[li + 48] * r;
    __syncthreads();
    int f = tid;
    v2f acc2[8];
    #pragma unroll
    for (int i = 0; i < 8; ++i) acc2[i] = (v2f){0.f, 0.f};
    for (int j = 0; j < D; ++j) {
        float wv = W1[j*FFNx + f];
        v2f wv2 = (v2f){wv, wv};
        const float4* hp = (const float4*)&h2t[j][0];
        float4 a0 = hp[0], a1 = hp[1], a2 = hp[2], a3 = hp[3];
        const v2f* a0v = (const v2f*)&a0;
        const v2f* a1v = (const v2f*)&a1;
        const v2f* a2v = (const v2f*)&a2;
        const v2f* a3v = (const v2f*)&a3;
        acc2[0] += a0v[0]*wv2;  acc2[1] += a0v[1]*wv2;
        acc2[2] += a1v[0]*wv2;  acc2[3] += a1v[1]*wv2;
        acc2[4] += a2v[0]*wv2;  acc2[5] += a2v[1]*wv2;
        acc2[6] += a3v[0]*wv2;  acc2[7] += a3v[1]*wv2;
    }
    #pragma unroll
    for (int i = 0; i < 8; ++i) {
        float ua = acc2[i].x;
        float ub = acc2[i].y;
        ua = 0.5f * ua * (1.0f + erff(ua * 0.70710678118654752f));
        ub = 0.5f * ub * (1.0f + erff(ub * 0.70710678118654752f));
        U[(t0 + 2*i)*FFNx + f]     = ua;
        U[(t0 + 2*i + 1)*FFNx + f] = ub;
    }
}

// ---------------- x += U @ W2 (transposed LDS, packed f32) ----------------
__global__ __launch_bounds__(256) void k_ffn2(
    float* __restrict__ X, const float* __restrict__ U,
    const float* __restrict__ W2) {
    __shared__ __align__(16) float ult[FFNx][20];  // [f][token]
    __shared__ float red[4][16][D];
    int tid = threadIdx.x;
    int t0 = blockIdx.x * 16;
    #pragma unroll
    for (int k = 0; k < 16; ++k) ult[tid][k] = U[(t0 + k)*FFNx + tid];
    __syncthreads();
    int d = tid & 63, fp = tid >> 6;
    v2f acc2[8];
    #pragma unroll
    for (int i = 0; i < 8; ++i) acc2[i] = (v2f){0.f, 0.f};
    for (int fo = 0; fo < 64; ++fo) {
        int f = fp*64 + fo;
        float wv = W2[f*D + d];
        v2f wv2 = (v2f){wv, wv};
        const float4* up = (const float4*)&ult[f][0];
        float4 u0 = up[0], u1 = up[1], u2 = up[2], u3 = up[3];
        const v2f* u0v = (const v2f*)&u0;
        const v2f* u1v = (const v2f*)&u1;
        const v2f* u2v = (const v2f*)&u2;
        const v2f* u3v = (const v2f*)&u3;
        acc2[0] += u0v[0]*wv2;  acc2[1] += u0v[1]*wv2;
        acc2[2] += u1v[0]*wv2;  acc2[3] += u1v[1]*wv2;
        acc2[4] += u2v[0]*wv2;  acc2[5] += u2v[1]*wv2;
        acc2[6] += u3v[0]*wv2;  acc2[7] += u3v[1]*wv2;
    }
    #pragma unroll
    for (int i = 0; i < 8; ++i) {
        red[fp][2*i][d]     = acc2[i].x;
        red[fp][2*i + 1][d] = acc2[i].y;
    }
    __syncthreads();
    int tk = tid >> 6;
    #pragma unroll
    for (int k = 0; k < 4; ++k) {
        int tt = tk + k*4;
        float sum = red[0][tt][d] + red[1][tt][d] + red[2][tt][d] + red[3][tt][d];
        X[(t0 + tt)*D + d] += sum;
    }
}

// ---------------- head ----------------
__global__ __launch_bounds__(256) void k_head(
    const float* __restrict__ X, const float* __restrict__ Wh,
    const float* __restrict__ bh, float* __restrict__ logit1,
    int* __restrict__ em) {
    int tid = threadIdx.x;
    int w = tid >> 6, d = tid & 63;
    int t = blockIdx.x*4 + w;
    float xv = X[t*D + d];
    float p0 = xv * Wh[d*2];
    float p1 = xv * Wh[d*2 + 1];
    #pragma unroll
    for (int off = 32; off; off >>= 1) {
        p0 += __shfl_xor(p0, off);
        p1 += __shfl_xor(p1, off);
    }
    if (d == 0) {
        float l0 = p0 + bh[0], l1 = p1 + bh[1];
        em[t] = (l0 > l1) ? 1 : 0;
        logit1[t] = l1;
    }
}

// ---------------- reg term ----------------
__global__ void k_reg(const float* __restrict__ logit1, float* __restrict__ outreg) {
    __shared__ float red[256];
    int tid = threadIdx.x;
    float s = 0.f;
    for (int i = tid; i < NT; i += 256) s += logit1[i];
    red[tid] = s;
    __syncthreads();
    for (int off = 128; off; off >>= 1) {
        if (tid < off) red[tid] += red[tid + off];
        __syncthreads();
    }
    if (tid == 0) *outreg = red[0] * (1.0f / NT);
}

// ---------------- per-batch scan ----------------
__global__ __launch_bounds__(256) void k_scan(const int* __restrict__ em,
                                              int* __restrict__ cp) {
    __shared__ int ssum[256], smax[256];
    __shared__ int sany, stot;
    int b = blockIdx.x, tid = threadIdx.x;
    const int* e = em + b*Ss;
    int base = tid * 8;
    int loc[8];
    int lsum = 0, lor = 0;
    #pragma unroll
    for (int i = 0; i < 8; ++i) { loc[i] = e[base + i]; lsum += loc[i]; lor |= loc[i]; }
    ssum[tid] = lor;
    __syncthreads();
    if (tid == 0) { int a = 0; for (int i = 0; i < 256; ++i) a |= ssum[i]; sany = a; }
    __syncthreads();
    int any = sany;
    __syncthreads();
    if (!any && tid == 255) { loc[7] = 1; lsum = 1; }
    int prev = (tid == 0) ? 1 : e[base - 1];
    if (!any && tid) prev = 0;
    int mk[8];
    int lmax = -1;
    #pragma unroll
    for (int i = 0; i < 8; ++i) {
        int pe = (i == 0) ? prev : loc[i - 1];
        if (i == 7 && !any && tid == 255) pe = e[base + 6];
        mk[i] = pe ? (base + i) : -1;
        lmax = max(lmax, mk[i]);
    }
    ssum[tid] = lsum; smax[tid] = lmax;
    __syncthreads();
    if (tid == 0) {
        int rs = 0, rm = -1;
        for (int i = 0; i < 256; ++i) {
            int ts = ssum[i], tm = smax[i];
            ssum[i] = rs; smax[i] = rm;
            rs += ts; rm = max(rm, tm);
        }
        stot = rs;
    }
    __syncthreads();
    int run = ssum[tid], rmax = smax[tid], tot = stot;
    int* cpb = cp + b*Ss;
    #pragma unroll
    for (int i = 0; i < 8; ++i) {
        int s = base + i;
        rmax = max(rmax, mk[i]);
        int chunk = run;
        run += loc[i];
        int pos = s - rmax;
        bool valid = (chunk < tot) && (chunk < MAXC) && (pos < MCL);
        cpb[s] = valid ? (chunk * MCL + pos) : -1;
    }
}

// ---------------- fill / scatter ----------------
__global__ void k_fill(float* __restrict__ out, const float* __restrict__ pad,
                       const int* __restrict__ padid) {
    int i = blockIdx.x * blockDim.x + threadIdx.x;
    constexpr int N4  = Bb * MAXC * MCL * D / 4;
    constexpr int NI4 = Bb * MAXC * MCL / 4;
    if (i < N4) {
        ((float4*)out)[i] = ((const float4*)pad)[i & 15];
    } else if (i < N4 + NI4) {
        float pv = (float)(*padid);
        float4 v; v.x = pv; v.y = pv; v.z = pv; v.w = pv;
        ((float4*)out)[i] = v;
    }
}

__global__ __launch_bounds__(256) void k_scatter(
    const float* __restrict__ X, const int* __restrict__ cp,
    const int* __restrict__ ids, float* __restrict__ out) {
    int tid = threadIdx.x;
    int w = tid >> 6, d = tid & 63;
    int t = blockIdx.x*4 + w;
    int c = cp[t];
    if (c < 0) return;
    int b = t >> 11;
    float* dst = out + ((size_t)(b * MAXC * MCL) + c) * D;
    dst[d] = X[t*D + d];
    if (d == 0)
        out[(size_t)Bb*MAXC*MCL*D + (size_t)b*MAXC*MCL + c] = (float)ids[t];
}

// ---------------- launch ----------------
extern "C" void kernel_launch(void* const* d_in, const int* in_sizes, int n_in,
                              void* d_out, int out_size, void* d_ws, size_t ws_size,
                              hipStream_t stream) {
    const float* x    = (const float*)d_in[0];
    const float* pad  = (const float*)d_in[1];
    const int*   xids = (const int*)  d_in[2];
    const int*   padid= (const int*)  d_in[3];
    const float* Wq   = (const float*)d_in[4];
    const float* Wk   = (const float*)d_in[5];
    const float* Wv   = (const float*)d_in[6];
    const float* Wo   = (const float*)d_in[7];
    const float* ln1  = (const float*)d_in[8];
    const float* ln2  = (const float*)d_in[9];
    const float* W1   = (const float*)d_in[10];
    const float* W2   = (const float*)d_in[11];
    const float* Wh   = (const float*)d_in[12];
    const float* bh   = (const float*)d_in[13];
    float* out = (float*)d_out;
    float* ws  = (float*)d_ws;

    float* X  = ws + WX;
    float* Qb = ws + WQ;
    float* KVb= ws + WKV;
    float* Ob = ws + WO;
    float* PBb= ws + WPB;
    float* Ub = ws + WU;
    float* L1b= ws + WL1;
    int*   EMb= (int*)(ws + WEM);
    int*   CPb= (int*)(ws + WCP);
    float* ct = ws + WCT;
    float* st = ws + WST;

    k_init<<<2048, 256, 0, stream>>>(x, X, ct, st);
    for (int l = 0; l < NL; ++l) {
        k_qkv <<<256, 256, 0, stream>>>(X, Wq + l*D*D, Wk + l*D*D, Wv + l*D*D,
                                        ln1 + l*D, ct, st, Qb, KVb);
        k_attn2<<<32*BPB, 256, 0, stream>>>(Qb, KVb, PBb);
        k_comb <<<32*16, 128, 0, stream>>>(PBb, Ob);
        k_post1<<<256, 256, 0, stream>>>(X, Ob, Wo + l*D*D);
        k_ffn1<<<NT/16, 256, 0, stream>>>(X, ln2 + l*D, W1 + l*D*FFNx, Ub);
        k_ffn2<<<NT/16, 256, 0, stream>>>(X, Ub, W2 + l*FFNx*D);
    }
    k_head<<<NT/4, 256, 0, stream>>>(X, Wh, bh, L1b, EMb);
    k_reg <<<1, 256, 0, stream>>>(L1b, out + (size_t)Bb*MAXC*MCL*D + Bb*MAXC*MCL);
    k_scan<<<Bb, 256, 0, stream>>>(EMb, CPb);
    k_fill<<<(Bb*MAXC*MCL*D/4 + Bb*MAXC*MCL/4 + 255)/256, 256, 0, stream>>>(out, pad, padid);
    k_scatter<<<NT/4, 256, 0, stream>>>(X, CPb, xids, out);
}

// Round 10
// 353.603 us; speedup vs baseline: 1.3705x; 1.1785x over previous
//
#include <hip/hip_runtime.h>
#include <math.h>

// ---------------- problem constants (fixed by setup_inputs) ----------------
constexpr int D   = 64;
constexpr int H   = 8;
constexpr int HD  = 8;
constexpr int NL  = 3;
constexpr int FFNx= 256;
constexpr int Bb  = 4;
constexpr int Ss  = 2048;
constexpr int NT  = Bb * Ss;        // 8192 tokens
constexpr int MAXC= 1024;
constexpr int MCL = 16;

// attention task decomposition: uniform tasks, chunk-major enumeration
constexpr int QW   = 128;            // queries per wave (2 per lane)
constexpr int CH   = 128;            // keys per chunk task (== QW -> uniform)
constexpr int TPB  = 136;            // tasks per (b,h): sum_{s=0..15} (16-s)
constexpr int BPB  = 34;             // blocks per (b,h) (4 waves each)
constexpr int PBSZ = 1152;           // floats per partial: l(128) + o(1024)

// ---------------- workspace layout (float elements) ----------------
constexpr size_t WX  = 0;                        // [NT*D] = 524288
constexpr size_t WQ  = 524288;                   // [NT*D] (U alias, needs NT*FFN)
constexpr size_t WKV = 2621440;                  // [32*2048*16] interleaved K|V
constexpr size_t WO  = 3670016;                  // [NT*D]
constexpr size_t WPB = 4194304;                  // [32*TPB*PBSZ] attn partials
constexpr size_t WU  = WQ;                       // [NT*FFN] aliases Q
constexpr size_t WL1 = 9764864;                  // [NT]
constexpr size_t WEM = WL1 + NT;                 // [NT] int
constexpr size_t WCP = WEM + NT;                 // [NT] int
constexpr size_t WCT = WCP + NT;                 // [Ss*4]
constexpr size_t WST = WCT + Ss*4;               // [Ss*4]  (end ~9.81M floats)

constexpr float LOG2E = 1.4426950408889634f;

typedef float v2f  __attribute__((ext_vector_type(2)));
typedef float f16v __attribute__((ext_vector_type(16)));
// constant-address-space pointer: keys are wave-uniform & read-only inside
// k_attn2, so loads through this become s_load_dwordx16 (scalar pipe, SGPRs)
using ckv_t = const __attribute__((address_space(4))) f16v*;

__device__ __forceinline__ float rdlane(float v, int l) {
    return __builtin_bit_cast(float, __builtin_amdgcn_readlane(__builtin_bit_cast(int, v), l));
}

// ---------------- init: copy x -> X, build rope tables ----------------
__global__ void k_init(const float* __restrict__ x, float* __restrict__ X,
                       float* __restrict__ ct, float* __restrict__ st) {
    int i = blockIdx.x * blockDim.x + threadIdx.x;
    constexpr int N4 = NT * D / 4;
    if (i < N4) ((float4*)X)[i] = ((const float4*)x)[i];
    if (i < Ss * 4) {
        int s = i >> 2, f = i & 3;
        const float fr[4] = {1.0f, 0.1f, 0.01f, 0.001f};
        float ang = (float)s * fr[f];
        ct[i] = cosf(ang);
        st[i] = sinf(ang);
    }
}

// ---------------- rmsnorm + QKV + rope (wave-per-token, readlane bcast) ----
__global__ __launch_bounds__(256) void k_qkv(
    const float* __restrict__ X, const float* __restrict__ Wq,
    const float* __restrict__ Wk, const float* __restrict__ Wv,
    const float* __restrict__ g1, const float* __restrict__ ct,
    const float* __restrict__ st, float* __restrict__ Q,
    float* __restrict__ KV) {
    __shared__ float wq_s[D*D], wk_s[D*D], wv_s[D*D];
    __shared__ float g_s[D];
    int tid = threadIdx.x;
    for (int i = tid; i < D*D; i += 256) {
        wq_s[i] = Wq[i]; wk_s[i] = Wk[i]; wv_s[i] = Wv[i];
    }
    if (tid < D) g_s[tid] = g1[tid];
    __syncthreads();
    int w = tid >> 6, d = tid & 63;
    int t0 = blockIdx.x * 32;
    for (int it = 0; it < 8; ++it) {
        int t = t0 + it*4 + w;
        float xv = X[t*D + d];
        float ss = xv * xv;
        #pragma unroll
        for (int off = 32; off; off >>= 1) ss += __shfl_xor(ss, off);
        float r = 1.0f / sqrtf(ss * (1.0f/D) + 1e-6f);
        float h = xv * g_s[d] * r;
        float aq = 0.f, ak = 0.f, av = 0.f;
        #pragma unroll
        for (int j = 0; j < D; ++j) {
            float hj = rdlane(h, j);
            aq += hj * wq_s[j*D + d];
            ak += hj * wk_s[j*D + d];
            av += hj * wv_s[j*D + d];
        }
        int s  = t & (Ss - 1);
        int e  = d & 7;
        int fi = e & 3;
        float c  = ct[s*4 + fi];
        float sn = st[s*4 + fi];
        float pq = __shfl_xor(aq, 4);
        float pk = __shfl_xor(ak, 4);
        float rq, rk;
        if (e < 4) { rq = aq*c - pq*sn; rk = ak*c - pk*sn; }
        else       { rq = pq*sn + aq*c; rk = pk*sn + ak*c; }
        Q[t*D + d] = rq;
        int bq = t >> 11;
        int hh = d >> 3;
        float* kvp = KV + ((((size_t)(bq*H + hh))*Ss + s) << 4);
        kvp[e]     = rk;
        kvp[8 + e] = av;
    }
}

// ---------------- attention 128-key loop: KV via s_load (scalar pipe) -----
// kvs is an AS(4) pointer with wave-uniform address: each key is ONE
// s_load_dwordx16 into SGPRs (zero VALU cost); every v_fma then uses the
// key element as its single SGPR operand. 36 VALU + 1 SMEM per key.
template<bool DIAG>
__device__ __forceinline__ void attn_loop(
    ckv_t kvs, int L,
    float4 qa0, float4 qb0, float4 qa1, float4 qb1,
    float& l0r, float& l1r, float* __restrict__ o0, float* __restrict__ o1) {
    float l0 = 0.f, l1 = 0.f;
    #pragma unroll 4
    for (int j = 0; j < CH; ++j) {
        f16v kv = kvs[j];
        float s0 = kv[0]*qa0.x + kv[1]*qa0.y + kv[2]*qa0.z + kv[3]*qa0.w
                 + kv[4]*qb0.x + kv[5]*qb0.y + kv[6]*qb0.z + kv[7]*qb0.w;
        float s1 = kv[0]*qa1.x + kv[1]*qa1.y + kv[2]*qa1.z + kv[3]*qa1.w
                 + kv[4]*qb1.x + kv[5]*qb1.y + kv[6]*qb1.z + kv[7]*qb1.w;
        if (DIAG) {
            if (j > L)      s0 = -1e30f;
            if (j > L + 64) s1 = -1e30f;
        }
        float p0 = __builtin_amdgcn_exp2f(s0);
        float p1 = __builtin_amdgcn_exp2f(s1);
        l0 += p0; l1 += p1;
        o0[0] += p0*kv[8];  o0[1] += p0*kv[9];  o0[2] += p0*kv[10]; o0[3] += p0*kv[11];
        o0[4] += p0*kv[12]; o0[5] += p0*kv[13]; o0[6] += p0*kv[14]; o0[7] += p0*kv[15];
        o1[0] += p1*kv[8];  o1[1] += p1*kv[9];  o1[2] += p1*kv[10]; o1[3] += p1*kv[11];
        o1[4] += p1*kv[12]; o1[5] += p1*kv[13]; o1[6] += p1*kv[14]; o1[7] += p1*kv[15];
    }
    l0r = l0; l1r = l1;
}

// ---------------- causal attention: scalar-pipe KV, XCD-pinned ------------
// blockIdx = xcd + 8*slot; bh = (slot/BPB)*8 + xcd (all 34 blocks of a bh
// on one XCD -> its 128KB KV stays L2-resident). Task ids made wave-uniform
// via readfirstlane so KV addresses select the SMEM path.
__global__ __launch_bounds__(256) void k_attn2(
    const float* __restrict__ Qg, const float* __restrict__ KV,
    float* __restrict__ PB) {
    int xcd  = blockIdx.x & 7;
    int slot = blockIdx.x >> 3;
    int bhg  = slot / BPB;
    int blk  = slot - bhg * BPB;
    int bh   = bhg * 8 + xcd;
    int wvu  = __builtin_amdgcn_readfirstlane(threadIdx.x >> 6); // uniform
    int widb = blk * 4 + wvu;                  // task 0..135 within bh
    int L = threadIdx.x & 63;
    int rem = widb;
    int s = 0;
    while (rem >= 16 - s) { rem -= 16 - s; ++s; }
    int t = s + rem;
    int b = bh >> 3, h = bh & 7;
    int qmin = t * QW;
    int k0 = s * CH;

    const float SC = 0.35355339059327373f * LOG2E;   // 1/sqrt(8) * log2(e)
    const float* qp = Qg + ((size_t)(b*Ss + qmin + L))*D + h*HD;
    float4 qa0 = *(const float4*)(qp);
    float4 qb0 = *(const float4*)(qp + 4);
    float4 qa1 = *(const float4*)(qp + 64*D);
    float4 qb1 = *(const float4*)(qp + 64*D + 4);
    qa0.x*=SC; qa0.y*=SC; qa0.z*=SC; qa0.w*=SC;
    qb0.x*=SC; qb0.y*=SC; qb0.z*=SC; qb0.w*=SC;
    qa1.x*=SC; qa1.y*=SC; qa1.z*=SC; qa1.w*=SC;
    qb1.x*=SC; qb1.y*=SC; qb1.z*=SC; qb1.w*=SC;

    float l0, l1;
    float o0[8] = {0,0,0,0,0,0,0,0};
    float o1[8] = {0,0,0,0,0,0,0,0};

    ckv_t kvs = (ckv_t)(unsigned long long)(KV + (((size_t)bh*Ss + k0) << 4));
    if (s == t) attn_loop<true >(kvs, L, qa0, qb0, qa1, qb1, l0, l1, o0, o1);
    else        attn_loop<false>(kvs, L, qa0, qb0, qa1, qb1, l0, l1, o0, o1);

    float* pb = PB + ((size_t)bh * TPB + widb) * PBSZ;
    pb[L]      = l0;
    pb[64 + L] = l1;
    #pragma unroll
    for (int e = 0; e < 8; ++e) {
        pb[128 + e*128 + L]      = o0[e];
        pb[128 + e*128 + 64 + L] = o1[e];
    }
}

// ---------------- combine partials -> O (plain sums, fixed bias) ----------
__global__ __launch_bounds__(128) void k_comb(const float* __restrict__ PB,
                                              float* __restrict__ Og) {
    int qs = threadIdx.x;           // 0..127
    int t  = blockIdx.x & 15;
    int bh = blockIdx.x >> 4;
    int b = bh >> 3, h = bh & 7;
    float Lx = 0.f;
    float O[8] = {0,0,0,0,0,0,0,0};
    for (int s3 = 0; s3 <= t; ++s3) {
        int idx = 16*s3 - (s3*(s3-1))/2 + (t - s3);
        const float* pb = PB + (size_t)(bh*TPB + idx) * PBSZ;
        Lx += pb[qs];
        #pragma unroll
        for (int e = 0; e < 8; ++e) O[e] += pb[128 + e*128 + qs];
    }
    float inv = 1.0f / Lx;
    float* op = Og + ((size_t)(b*Ss + t*QW + qs))*D + h*HD;
    #pragma unroll
    for (int e = 0; e < 8; ++e) op[e] = O[e] * inv;
}

// ---------------- x += O @ Wo (readlane bcast) ----------------
__global__ __launch_bounds__(256) void k_post1(
    float* __restrict__ X, const float* __restrict__ Og,
    const float* __restrict__ Wo) {
    __shared__ float ws_[D*D];
    int tid = threadIdx.x;
    for (int i = tid; i < D*D; i += 256) ws_[i] = Wo[i];
    __syncthreads();
    int w = tid >> 6, d = tid & 63;
    int t0 = blockIdx.x * 32;
    for (int it = 0; it < 8; ++it) {
        int t = t0 + it*4 + w;
        float ov = Og[t*D + d];
        float a = 0.f;
        #pragma unroll
        for (int j = 0; j < D; ++j) a += rdlane(ov, j) * ws_[j*D + d];
        X[t*D + d] += a;
    }
}

// ---------------- rms2 + W1 + gelu -> U (transposed LDS, packed f32) ------
__global__ __launch_bounds__(256) void k_ffn1(
    const float* __restrict__ X, const float* __restrict__ g2,
    const float* __restrict__ W1, float* __restrict__ U) {
    __shared__ __align__(16) float h2t[64][20];   // [dim][token], 80B rows
    __shared__ float part[16][16];
    __shared__ float g_s[D];
    int tid = threadIdx.x;
    if (tid < D) g_s[tid] = g2[tid];
    int t0 = blockIdx.x * 16;
    int tk = tid >> 4, li = tid & 15;
    float x0 = X[(t0+tk)*D + li];
    float x1 = X[(t0+tk)*D + li + 16];
    float x2 = X[(t0+tk)*D + li + 32];
    float x3 = X[(t0+tk)*D + li + 48];
    part[tk][li] = x0*x0 + x1*x1 + x2*x2 + x3*x3;
    __syncthreads();
    if (tid < 16) {
        float s = 0.f;
        #pragma unroll
        for (int i = 0; i < 16; ++i) s += part[tid][i];
        part[tid][0] = 1.0f / sqrtf(s * (1.0f/D) + 1e-6f);
    }
    __syncthreads();
    float r = part[tk][0];
    h2t[li][tk]      = x0 * g_s[li]      * r;
    h2t[li + 16][tk] = x1 * g_s[li + 16] * r;
    h2t[li + 32][tk] = x2 * g_s[li + 32] * r;
    h2t[li + 48][tk] = x3 * g_s[li + 48] * r;
    __syncthreads();
    int f = tid;
    v2f acc2[8];
    #pragma unroll
    for (int i = 0; i < 8; ++i) acc2[i] = (v2f){0.f, 0.f};
    for (int j = 0; j < D; ++j) {
        float wv = W1[j*FFNx + f];
        v2f wv2 = (v2f){wv, wv};
        const float4* hp = (const float4*)&h2t[j][0];
        float4 a0 = hp[0], a1 = hp[1], a2 = hp[2], a3 = hp[3];
        const v2f* a0v = (const v2f*)&a0;
        const v2f* a1v = (const v2f*)&a1;
        const v2f* a2v = (const v2f*)&a2;
        const v2f* a3v = (const v2f*)&a3;
        acc2[0] += a0v[0]*wv2;  acc2[1] += a0v[1]*wv2;
        acc2[2] += a1v[0]*wv2;  acc2[3] += a1v[1]*wv2;
        acc2[4] += a2v[0]*wv2;  acc2[5] += a2v[1]*wv2;
        acc2[6] += a3v[0]*wv2;  acc2[7] += a3v[1]*wv2;
    }
    #pragma unroll
    for (int i = 0; i < 8; ++i) {
        float ua = acc2[i].x;
        float ub = acc2[i].y;
        ua = 0.5f * ua * (1.0f + erff(ua * 0.70710678118654752f));
        ub = 0.5f * ub * (1.0f + erff(ub * 0.70710678118654752f));
        U[(t0 + 2*i)*FFNx + f]     = ua;
        U[(t0 + 2*i + 1)*FFNx + f] = ub;
    }
}

// ---------------- x += U @ W2 (transposed LDS, packed f32) ----------------
__global__ __launch_bounds__(256) void k_ffn2(
    float* __restrict__ X, const float* __restrict__ U,
    const float* __restrict__ W2) {
    __shared__ __align__(16) float ult[FFNx][20];  // [f][token]
    __shared__ float red[4][16][D];
    int tid = threadIdx.x;
    int t0 = blockIdx.x * 16;
    #pragma unroll
    for (int k = 0; k < 16; ++k) ult[tid][k] = U[(t0 + k)*FFNx + tid];
    __syncthreads();
    int d = tid & 63, fp = tid >> 6;
    v2f acc2[8];
    #pragma unroll
    for (int i = 0; i < 8; ++i) acc2[i] = (v2f){0.f, 0.f};
    for (int fo = 0; fo < 64; ++fo) {
        int f = fp*64 + fo;
        float wv = W2[f*D + d];
        v2f wv2 = (v2f){wv, wv};
        const float4* up = (const float4*)&ult[f][0];
        float4 u0 = up[0], u1 = up[1], u2 = up[2], u3 = up[3];
        const v2f* u0v = (const v2f*)&u0;
        const v2f* u1v = (const v2f*)&u1;
        const v2f* u2v = (const v2f*)&u2;
        const v2f* u3v = (const v2f*)&u3;
        acc2[0] += u0v[0]*wv2;  acc2[1] += u0v[1]*wv2;
        acc2[2] += u1v[0]*wv2;  acc2[3] += u1v[1]*wv2;
        acc2[4] += u2v[0]*wv2;  acc2[5] += u2v[1]*wv2;
        acc2[6] += u3v[0]*wv2;  acc2[7] += u3v[1]*wv2;
    }
    #pragma unroll
    for (int i = 0; i < 8; ++i) {
        red[fp][2*i][d]     = acc2[i].x;
        red[fp][2*i + 1][d] = acc2[i].y;
    }
    __syncthreads();
    int tk = tid >> 6;
    #pragma unroll
    for (int k = 0; k < 4; ++k) {
        int tt = tk + k*4;
        float sum = red[0][tt][d] + red[1][tt][d] + red[2][tt][d] + red[3][tt][d];
        X[(t0 + tt)*D + d] += sum;
    }
}

// ---------------- head ----------------
__global__ __launch_bounds__(256) void k_head(
    const float* __restrict__ X, const float* __restrict__ Wh,
    const float* __restrict__ bh, float* __restrict__ logit1,
    int* __restrict__ em) {
    int tid = threadIdx.x;
    int w = tid >> 6, d = tid & 63;
    int t = blockIdx.x*4 + w;
    float xv = X[t*D + d];
    float p0 = xv * Wh[d*2];
    float p1 = xv * Wh[d*2 + 1];
    #pragma unroll
    for (int off = 32; off; off >>= 1) {
        p0 += __shfl_xor(p0, off);
        p1 += __shfl_xor(p1, off);
    }
    if (d == 0) {
        float l0 = p0 + bh[0], l1 = p1 + bh[1];
        em[t] = (l0 > l1) ? 1 : 0;
        logit1[t] = l1;
    }
}

// ---------------- reg term ----------------
__global__ void k_reg(const float* __restrict__ logit1, float* __restrict__ outreg) {
    __shared__ float red[256];
    int tid = threadIdx.x;
    float s = 0.f;
    for (int i = tid; i < NT; i += 256) s += logit1[i];
    red[tid] = s;
    __syncthreads();
    for (int off = 128; off; off >>= 1) {
        if (tid < off) red[tid] += red[tid + off];
        __syncthreads();
    }
    if (tid == 0) *outreg = red[0] * (1.0f / NT);
}

// ---------------- per-batch scan ----------------
__global__ __launch_bounds__(256) void k_scan(const int* __restrict__ em,
                                              int* __restrict__ cp) {
    __shared__ int ssum[256], smax[256];
    __shared__ int sany, stot;
    int b = blockIdx.x, tid = threadIdx.x;
    const int* e = em + b*Ss;
    int base = tid * 8;
    int loc[8];
    int lsum = 0, lor = 0;
    #pragma unroll
    for (int i = 0; i < 8; ++i) { loc[i] = e[base + i]; lsum += loc[i]; lor |= loc[i]; }
    ssum[tid] = lor;
    __syncthreads();
    if (tid == 0) { int a = 0; for (int i = 0; i < 256; ++i) a |= ssum[i]; sany = a; }
    __syncthreads();
    int any = sany;
    __syncthreads();
    if (!any && tid == 255) { loc[7] = 1; lsum = 1; }
    int prev = (tid == 0) ? 1 : e[base - 1];
    if (!any && tid) prev = 0;
    int mk[8];
    int lmax = -1;
    #pragma unroll
    for (int i = 0; i < 8; ++i) {
        int pe = (i == 0) ? prev : loc[i - 1];
        if (i == 7 && !any && tid == 255) pe = e[base + 6];
        mk[i] = pe ? (base + i) : -1;
        lmax = max(lmax, mk[i]);
    }
    ssum[tid] = lsum; smax[tid] = lmax;
    __syncthreads();
    if (tid == 0) {
        int rs = 0, rm = -1;
        for (int i = 0; i < 256; ++i) {
            int ts = ssum[i], tm = smax[i];
            ssum[i] = rs; smax[i] = rm;
            rs += ts; rm = max(rm, tm);
        }
        stot = rs;
    }
    __syncthreads();
    int run = ssum[tid], rmax = smax[tid], tot = stot;
    int* cpb = cp + b*Ss;
    #pragma unroll
    for (int i = 0; i < 8; ++i) {
        int s = base + i;
        rmax = max(rmax, mk[i]);
        int chunk = run;
        run += loc[i];
        int pos = s - rmax;
        bool valid = (chunk < tot) && (chunk < MAXC) && (pos < MCL);
        cpb[s] = valid ? (chunk * MCL + pos) : -1;
    }
}

// ---------------- fill / scatter ----------------
__global__ void k_fill(float* __restrict__ out, const float* __restrict__ pad,
                       const int* __restrict__ padid) {
    int i = blockIdx.x * blockDim.x + threadIdx.x;
    constexpr int N4  = Bb * MAXC * MCL * D / 4;
    constexpr int NI4 = Bb * MAXC * MCL / 4;
    if (i < N4) {
        ((float4*)out)[i] = ((const float4*)pad)[i & 15];
    } else if (i < N4 + NI4) {
        float pv = (float)(*padid);
        float4 v; v.x = pv; v.y = pv; v.z = pv; v.w = pv;
        ((float4*)out)[i] = v;
    }
}

__global__ __launch_bounds__(256) void k_scatter(
    const float* __restrict__ X, const int* __restrict__ cp,
    const int* __restrict__ ids, float* __restrict__ out) {
    int tid = threadIdx.x;
    int w = tid >> 6, d = tid & 63;
    int t = blockIdx.x*4 + w;
    int c = cp[t];
    if (c < 0) return;
    int b = t >> 11;
    float* dst = out + ((size_t)(b * MAXC * MCL) + c) * D;
    dst[d] = X[t*D + d];
    if (d == 0)
        out[(size_t)Bb*MAXC*MCL*D + (size_t)b*MAXC*MCL + c] = (float)ids[t];
}

// ---------------- launch ----------------
extern "C" void kernel_launch(void* const* d_in, const int* in_sizes, int n_in,
                              void* d_out, int out_size, void* d_ws, size_t ws_size,
                              hipStream_t stream) {
    const float* x    = (const float*)d_in[0];
    const float* pad  = (const float*)d_in[1];
    const int*   xids = (const int*)  d_in[2];
    const int*   padid= (const int*)  d_in[3];
    const float* Wq   = (const float*)d_in[4];
    const float* Wk   = (const float*)d_in[5];
    const float* Wv   = (const float*)d_in[6];
    const float* Wo   = (const float*)d_in[7];
    const float* ln1  = (const float*)d_in[8];
    const float* ln2  = (const float*)d_in[9];
    const float* W1   = (const float*)d_in[10];
    const float* W2   = (const float*)d_in[11];
    const float* Wh   = (const float*)d_in[12];
    const float* bh   = (const float*)d_in[13];
    float* out = (float*)d_out;
    float* ws  = (float*)d_ws;

    float* X  = ws + WX;
    float* Qb = ws + WQ;
    float* KVb= ws + WKV;
    float* Ob = ws + WO;
    float* PBb= ws + WPB;
    float* Ub = ws + WU;
    float* L1b= ws + WL1;
    int*   EMb= (int*)(ws + WEM);
    int*   CPb= (int*)(ws + WCP);
    float* ct = ws + WCT;
    float* st = ws + WST;

    k_init<<<2048, 256, 0, stream>>>(x, X, ct, st);
    for (int l = 0; l < NL; ++l) {
        k_qkv <<<256, 256, 0, stream>>>(X, Wq + l*D*D, Wk + l*D*D, Wv + l*D*D,
                                        ln1 + l*D, ct, st, Qb, KVb);
        k_attn2<<<32*BPB, 256, 0, stream>>>(Qb, KVb, PBb);
        k_comb <<<32*16, 128, 0, stream>>>(PBb, Ob);
        k_post1<<<256, 256, 0, stream>>>(X, Ob, Wo + l*D*D);
        k_ffn1<<<NT/16, 256, 0, stream>>>(X, ln2 + l*D, W1 + l*D*FFNx, Ub);
        k_ffn2<<<NT/16, 256, 0, stream>>>(X, Ub, W2 + l*FFNx*D);
    }
    k_head<<<NT/4, 256, 0, stream>>>(X, Wh, bh, L1b, EMb);
    k_reg <<<1, 256, 0, stream>>>(L1b, out + (size_t)Bb*MAXC*MCL*D + Bb*MAXC*MCL);
    k_scan<<<Bb, 256, 0, stream>>>(EMb, CPb);
    k_fill<<<(Bb*MAXC*MCL*D/4 + Bb*MAXC*MCL/4 + 255)/256, 256, 0, stream>>>(out, pad, padid);
    k_scatter<<<NT/4, 256, 0, stream>>>(X, CPb, xids, out);
}

// Round 11
// 329.988 us; speedup vs baseline: 1.4686x; 1.0716x over previous
//
#include <hip/hip_runtime.h>
#include <math.h>

// ---------------- problem constants (fixed by setup_inputs) ----------------
constexpr int D   = 64;
constexpr int H   = 8;
constexpr int HD  = 8;
constexpr int NL  = 3;
constexpr int FFNx= 256;
constexpr int Bb  = 4;
constexpr int Ss  = 2048;
constexpr int NT  = Bb * Ss;        // 8192 tokens
constexpr int MAXC= 1024;
constexpr int MCL = 16;

// attention task decomposition: uniform tasks, chunk-major enumeration
constexpr int QW   = 128;            // queries per wave (2 per lane)
constexpr int CH   = 128;            // keys per chunk task (== QW -> uniform)
constexpr int TPB  = 136;            // tasks per (b,h): sum_{s=0..15} (16-s)
constexpr int BPB  = 34;             // blocks per (b,h) (4 waves each)
constexpr int PBSZ = 1152;           // floats per partial: l(128) + o(1024)

// ---------------- workspace layout (float elements) ----------------
constexpr size_t WX  = 0;                        // [NT*D] = 524288
constexpr size_t WQ  = 524288;                   // [NT*D] (U alias, needs NT*FFN)
constexpr size_t WKV = 2621440;                  // [32*2048*16] interleaved K|V
constexpr size_t WO  = 3670016;                  // [NT*D]
constexpr size_t WPB = 4194304;                  // [32*TPB*PBSZ] attn partials
constexpr size_t WU  = WQ;                       // [NT*FFN] aliases Q
constexpr size_t WL1 = 9764864;                  // [NT]
constexpr size_t WEM = WL1 + NT;                 // [NT] int
constexpr size_t WCP = WEM + NT;                 // [NT] int
constexpr size_t WCT = WCP + NT;                 // [Ss*4]
constexpr size_t WST = WCT + Ss*4;               // [Ss*4]  (end ~9.81M floats)

constexpr float LOG2E = 1.4426950408889634f;

typedef float v2f  __attribute__((ext_vector_type(2)));
typedef float f16v __attribute__((ext_vector_type(16)));
// constant-address-space pointer: keys are wave-uniform & read-only inside
// k_attn2, so loads through this become s_load_dwordx16 (scalar pipe, SGPRs)
using ckv_t = const __attribute__((address_space(4))) f16v*;

__device__ __forceinline__ float rdlane(float v, int l) {
    return __builtin_bit_cast(float, __builtin_amdgcn_readlane(__builtin_bit_cast(int, v), l));
}

// ---------------- init: copy x -> X, build rope tables ----------------
__global__ void k_init(const float* __restrict__ x, float* __restrict__ X,
                       float* __restrict__ ct, float* __restrict__ st) {
    int i = blockIdx.x * blockDim.x + threadIdx.x;
    constexpr int N4 = NT * D / 4;
    if (i < N4) ((float4*)X)[i] = ((const float4*)x)[i];
    if (i < Ss * 4) {
        int s = i >> 2, f = i & 3;
        const float fr[4] = {1.0f, 0.1f, 0.01f, 0.001f};
        float ang = (float)s * fr[f];
        ct[i] = cosf(ang);
        st[i] = sinf(ang);
    }
}

// ---------------- rmsnorm + QKV + rope (wave-per-token, readlane bcast) ----
__global__ __launch_bounds__(256) void k_qkv(
    const float* __restrict__ X, const float* __restrict__ Wq,
    const float* __restrict__ Wk, const float* __restrict__ Wv,
    const float* __restrict__ g1, const float* __restrict__ ct,
    const float* __restrict__ st, float* __restrict__ Q,
    float* __restrict__ KV) {
    __shared__ float wq_s[D*D], wk_s[D*D], wv_s[D*D];
    __shared__ float g_s[D];
    int tid = threadIdx.x;
    for (int i = tid; i < D*D; i += 256) {
        wq_s[i] = Wq[i]; wk_s[i] = Wk[i]; wv_s[i] = Wv[i];
    }
    if (tid < D) g_s[tid] = g1[tid];
    __syncthreads();
    int w = tid >> 6, d = tid & 63;
    int t0 = blockIdx.x * 32;
    for (int it = 0; it < 8; ++it) {
        int t = t0 + it*4 + w;
        float xv = X[t*D + d];
        float ss = xv * xv;
        #pragma unroll
        for (int off = 32; off; off >>= 1) ss += __shfl_xor(ss, off);
        float r = 1.0f / sqrtf(ss * (1.0f/D) + 1e-6f);
        float h = xv * g_s[d] * r;
        float aq = 0.f, ak = 0.f, av = 0.f;
        #pragma unroll
        for (int j = 0; j < D; ++j) {
            float hj = rdlane(h, j);
            aq += hj * wq_s[j*D + d];
            ak += hj * wk_s[j*D + d];
            av += hj * wv_s[j*D + d];
        }
        int s  = t & (Ss - 1);
        int e  = d & 7;
        int fi = e & 3;
        float c  = ct[s*4 + fi];
        float sn = st[s*4 + fi];
        float pq = __shfl_xor(aq, 4);
        float pk = __shfl_xor(ak, 4);
        float rq, rk;
        if (e < 4) { rq = aq*c - pq*sn; rk = ak*c - pk*sn; }
        else       { rq = pq*sn + aq*c; rk = pk*sn + ak*c; }
        Q[t*D + d] = rq;
        int bq = t >> 11;
        int hh = d >> 3;
        float* kvp = KV + ((((size_t)(bq*H + hh))*Ss + s) << 4);
        kvp[e]     = rk;
        kvp[8 + e] = av;
    }
}

// ---------------- attention 128-key loop: s_load KV + packed-f32 math -----
// kvs is AS(4) with wave-uniform address: one s_load_dwordx16 per key into
// SGPRs; each v_pk_fma_f32 then broadcasts the SGPR key element into both
// halves (op_sel), processing both queries at once. ~19 VALU + 1 SMEM /key.
template<bool DIAG>
__device__ __forceinline__ void attn_loop(
    ckv_t kvs, int L,
    const v2f* __restrict__ q01, v2f& l01, v2f* __restrict__ oP) {
    #pragma unroll 4
    for (int j = 0; j < CH; ++j) {
        f16v kv = kvs[j];
        v2f acc;
        acc  = q01[0] * (v2f){kv[0], kv[0]};
        acc += q01[1] * (v2f){kv[1], kv[1]};
        acc += q01[2] * (v2f){kv[2], kv[2]};
        acc += q01[3] * (v2f){kv[3], kv[3]};
        acc += q01[4] * (v2f){kv[4], kv[4]};
        acc += q01[5] * (v2f){kv[5], kv[5]};
        acc += q01[6] * (v2f){kv[6], kv[6]};
        acc += q01[7] * (v2f){kv[7], kv[7]};
        if (DIAG) {
            if (j > L)      acc.x = -1e30f;
            if (j > L + 64) acc.y = -1e30f;
        }
        v2f p;
        p.x = __builtin_amdgcn_exp2f(acc.x);
        p.y = __builtin_amdgcn_exp2f(acc.y);
        l01 += p;
        oP[0] += p * (v2f){kv[8],  kv[8]};
        oP[1] += p * (v2f){kv[9],  kv[9]};
        oP[2] += p * (v2f){kv[10], kv[10]};
        oP[3] += p * (v2f){kv[11], kv[11]};
        oP[4] += p * (v2f){kv[12], kv[12]};
        oP[5] += p * (v2f){kv[13], kv[13]};
        oP[6] += p * (v2f){kv[14], kv[14]};
        oP[7] += p * (v2f){kv[15], kv[15]};
    }
}

// ---------------- causal attention: scalar-pipe KV, XCD-pinned ------------
// blockIdx = xcd + 8*slot; bh = (slot/BPB)*8 + xcd (all 34 blocks of a bh
// on one XCD -> its 128KB KV stays L2-resident). Task ids made wave-uniform
// via readfirstlane so KV addresses select the SMEM path.
__global__ __launch_bounds__(256) void k_attn2(
    const float* __restrict__ Qg, const float* __restrict__ KV,
    float* __restrict__ PB) {
    int xcd  = blockIdx.x & 7;
    int slot = blockIdx.x >> 3;
    int bhg  = slot / BPB;
    int blk  = slot - bhg * BPB;
    int bh   = bhg * 8 + xcd;
    int wvu  = __builtin_amdgcn_readfirstlane(threadIdx.x >> 6); // uniform
    int widb = blk * 4 + wvu;                  // task 0..135 within bh
    int L = threadIdx.x & 63;
    int rem = widb;
    int s = 0;
    while (rem >= 16 - s) { rem -= 16 - s; ++s; }
    int t = s + rem;
    int b = bh >> 3, h = bh & 7;
    int qmin = t * QW;
    int k0 = s * CH;

    const float SC = 0.35355339059327373f * LOG2E;   // 1/sqrt(8) * log2(e)
    const float* qp = Qg + ((size_t)(b*Ss + qmin + L))*D + h*HD;
    float4 qa0 = *(const float4*)(qp);
    float4 qb0 = *(const float4*)(qp + 4);
    float4 qa1 = *(const float4*)(qp + 64*D);
    float4 qb1 = *(const float4*)(qp + 64*D + 4);
    v2f q01[8];
    q01[0] = (v2f){qa0.x*SC, qa1.x*SC};
    q01[1] = (v2f){qa0.y*SC, qa1.y*SC};
    q01[2] = (v2f){qa0.z*SC, qa1.z*SC};
    q01[3] = (v2f){qa0.w*SC, qa1.w*SC};
    q01[4] = (v2f){qb0.x*SC, qb1.x*SC};
    q01[5] = (v2f){qb0.y*SC, qb1.y*SC};
    q01[6] = (v2f){qb0.z*SC, qb1.z*SC};
    q01[7] = (v2f){qb0.w*SC, qb1.w*SC};

    v2f l01 = (v2f){0.f, 0.f};
    v2f oP[8];
    #pragma unroll
    for (int e = 0; e < 8; ++e) oP[e] = (v2f){0.f, 0.f};

    ckv_t kvs = (ckv_t)(unsigned long long)(KV + (((size_t)bh*Ss + k0) << 4));
    if (s == t) attn_loop<true >(kvs, L, q01, l01, oP);
    else        attn_loop<false>(kvs, L, q01, l01, oP);

    float* pb = PB + ((size_t)bh * TPB + widb) * PBSZ;
    pb[L]      = l01.x;
    pb[64 + L] = l01.y;
    #pragma unroll
    for (int e = 0; e < 8; ++e) {
        pb[128 + e*128 + L]      = oP[e].x;
        pb[128 + e*128 + 64 + L] = oP[e].y;
    }
}

// ---------------- combine partials -> O (plain sums, fixed bias) ----------
__global__ __launch_bounds__(128) void k_comb(const float* __restrict__ PB,
                                              float* __restrict__ Og) {
    int qs = threadIdx.x;           // 0..127
    int t  = blockIdx.x & 15;
    int bh = blockIdx.x >> 4;
    int b = bh >> 3, h = bh & 7;
    float Lx = 0.f;
    float O[8] = {0,0,0,0,0,0,0,0};
    for (int s3 = 0; s3 <= t; ++s3) {
        int idx = 16*s3 - (s3*(s3-1))/2 + (t - s3);
        const float* pb = PB + (size_t)(bh*TPB + idx) * PBSZ;
        Lx += pb[qs];
        #pragma unroll
        for (int e = 0; e < 8; ++e) O[e] += pb[128 + e*128 + qs];
    }
    float inv = 1.0f / Lx;
    float* op = Og + ((size_t)(b*Ss + t*QW + qs))*D + h*HD;
    #pragma unroll
    for (int e = 0; e < 8; ++e) op[e] = O[e] * inv;
}

// ---------------- x += O @ Wo (readlane bcast) ----------------
__global__ __launch_bounds__(256) void k_post1(
    float* __restrict__ X, const float* __restrict__ Og,
    const float* __restrict__ Wo) {
    __shared__ float ws_[D*D];
    int tid = threadIdx.x;
    for (int i = tid; i < D*D; i += 256) ws_[i] = Wo[i];
    __syncthreads();
    int w = tid >> 6, d = tid & 63;
    int t0 = blockIdx.x * 32;
    for (int it = 0; it < 8; ++it) {
        int t = t0 + it*4 + w;
        float ov = Og[t*D + d];
        float a = 0.f;
        #pragma unroll
        for (int j = 0; j < D; ++j) a += rdlane(ov, j) * ws_[j*D + d];
        X[t*D + d] += a;
    }
}

// ---------------- rms2 + W1 + gelu -> U (transposed LDS, packed f32) ------
__global__ __launch_bounds__(256) void k_ffn1(
    const float* __restrict__ X, const float* __restrict__ g2,
    const float* __restrict__ W1, float* __restrict__ U) {
    __shared__ __align__(16) float h2t[64][20];   // [dim][token], 80B rows
    __shared__ float part[16][16];
    __shared__ float g_s[D];
    int tid = threadIdx.x;
    if (tid < D) g_s[tid] = g2[tid];
    int t0 = blockIdx.x * 16;
    int tk = tid >> 4, li = tid & 15;
    float x0 = X[(t0+tk)*D + li];
    float x1 = X[(t0+tk)*D + li + 16];
    float x2 = X[(t0+tk)*D + li + 32];
    float x3 = X[(t0+tk)*D + li + 48];
    part[tk][li] = x0*x0 + x1*x1 + x2*x2 + x3*x3;
    __syncthreads();
    if (tid < 16) {
        float s = 0.f;
        #pragma unroll
        for (int i = 0; i < 16; ++i) s += part[tid][i];
        part[tid][0] = 1.0f / sqrtf(s * (1.0f/D) + 1e-6f);
    }
    __syncthreads();
    float r = part[tk][0];
    h2t[li][tk]      = x0 * g_s[li]      * r;
    h2t[li + 16][tk] = x1 * g_s[li + 16] * r;
    h2t[li + 32][tk] = x2 * g_s[li + 32] * r;
    h2t[li + 48][tk] = x3 * g_s[li + 48] * r;
    __syncthreads();
    int f = tid;
    v2f acc2[8];
    #pragma unroll
    for (int i = 0; i < 8; ++i) acc2[i] = (v2f){0.f, 0.f};
    for (int j = 0; j < D; ++j) {
        float wv = W1[j*FFNx + f];
        v2f wv2 = (v2f){wv, wv};
        const float4* hp = (const float4*)&h2t[j][0];
        float4 a0 = hp[0], a1 = hp[1], a2 = hp[2], a3 = hp[3];
        const v2f* a0v = (const v2f*)&a0;
        const v2f* a1v = (const v2f*)&a1;
        const v2f* a2v = (const v2f*)&a2;
        const v2f* a3v = (const v2f*)&a3;
        acc2[0] += a0v[0]*wv2;  acc2[1] += a0v[1]*wv2;
        acc2[2] += a1v[0]*wv2;  acc2[3] += a1v[1]*wv2;
        acc2[4] += a2v[0]*wv2;  acc2[5] += a2v[1]*wv2;
        acc2[6] += a3v[0]*wv2;  acc2[7] += a3v[1]*wv2;
    }
    #pragma unroll
    for (int i = 0; i < 8; ++i) {
        float ua = acc2[i].x;
        float ub = acc2[i].y;
        ua = 0.5f * ua * (1.0f + erff(ua * 0.70710678118654752f));
        ub = 0.5f * ub * (1.0f + erff(ub * 0.70710678118654752f));
        U[(t0 + 2*i)*FFNx + f]     = ua;
        U[(t0 + 2*i + 1)*FFNx + f] = ub;
    }
}

// ---------------- x += U @ W2 (transposed LDS, packed f32) ----------------
__global__ __launch_bounds__(256) void k_ffn2(
    float* __restrict__ X, const float* __restrict__ U,
    const float* __restrict__ W2) {
    __shared__ __align__(16) float ult[FFNx][20];  // [f][token]
    __shared__ float red[4][16][D];
    int tid = threadIdx.x;
    int t0 = blockIdx.x * 16;
    #pragma unroll
    for (int k = 0; k < 16; ++k) ult[tid][k] = U[(t0 + k)*FFNx + tid];
    __syncthreads();
    int d = tid & 63, fp = tid >> 6;
    v2f acc2[8];
    #pragma unroll
    for (int i = 0; i < 8; ++i) acc2[i] = (v2f){0.f, 0.f};
    for (int fo = 0; fo < 64; ++fo) {
        int f = fp*64 + fo;
        float wv = W2[f*D + d];
        v2f wv2 = (v2f){wv, wv};
        const float4* up = (const float4*)&ult[f][0];
        float4 u0 = up[0], u1 = up[1], u2 = up[2], u3 = up[3];
        const v2f* u0v = (const v2f*)&u0;
        const v2f* u1v = (const v2f*)&u1;
        const v2f* u2v = (const v2f*)&u2;
        const v2f* u3v = (const v2f*)&u3;
        acc2[0] += u0v[0]*wv2;  acc2[1] += u0v[1]*wv2;
        acc2[2] += u1v[0]*wv2;  acc2[3] += u1v[1]*wv2;
        acc2[4] += u2v[0]*wv2;  acc2[5] += u2v[1]*wv2;
        acc2[6] += u3v[0]*wv2;  acc2[7] += u3v[1]*wv2;
    }
    #pragma unroll
    for (int i = 0; i < 8; ++i) {
        red[fp][2*i][d]     = acc2[i].x;
        red[fp][2*i + 1][d] = acc2[i].y;
    }
    __syncthreads();
    int tk = tid >> 6;
    #pragma unroll
    for (int k = 0; k < 4; ++k) {
        int tt = tk + k*4;
        float sum = red[0][tt][d] + red[1][tt][d] + red[2][tt][d] + red[3][tt][d];
        X[(t0 + tt)*D + d] += sum;
    }
}

// ---------------- head ----------------
__global__ __launch_bounds__(256) void k_head(
    const float* __restrict__ X, const float* __restrict__ Wh,
    const float* __restrict__ bh, float* __restrict__ logit1,
    int* __restrict__ em) {
    int tid = threadIdx.x;
    int w = tid >> 6, d = tid & 63;
    int t = blockIdx.x*4 + w;
    float xv = X[t*D + d];
    float p0 = xv * Wh[d*2];
    float p1 = xv * Wh[d*2 + 1];
    #pragma unroll
    for (int off = 32; off; off >>= 1) {
        p0 += __shfl_xor(p0, off);
        p1 += __shfl_xor(p1, off);
    }
    if (d == 0) {
        float l0 = p0 + bh[0], l1 = p1 + bh[1];
        em[t] = (l0 > l1) ? 1 : 0;
        logit1[t] = l1;
    }
}

// ---------------- reg term ----------------
__global__ void k_reg(const float* __restrict__ logit1, float* __restrict__ outreg) {
    __shared__ float red[256];
    int tid = threadIdx.x;
    float s = 0.f;
    for (int i = tid; i < NT; i += 256) s += logit1[i];
    red[tid] = s;
    __syncthreads();
    for (int off = 128; off; off >>= 1) {
        if (tid < off) red[tid] += red[tid + off];
        __syncthreads();
    }
    if (tid == 0) *outreg = red[0] * (1.0f / NT);
}

// ---------------- per-batch scan ----------------
__global__ __launch_bounds__(256) void k_scan(const int* __restrict__ em,
                                              int* __restrict__ cp) {
    __shared__ int ssum[256], smax[256];
    __shared__ int sany, stot;
    int b = blockIdx.x, tid = threadIdx.x;
    const int* e = em + b*Ss;
    int base = tid * 8;
    int loc[8];
    int lsum = 0, lor = 0;
    #pragma unroll
    for (int i = 0; i < 8; ++i) { loc[i] = e[base + i]; lsum += loc[i]; lor |= loc[i]; }
    ssum[tid] = lor;
    __syncthreads();
    if (tid == 0) { int a = 0; for (int i = 0; i < 256; ++i) a |= ssum[i]; sany = a; }
    __syncthreads();
    int any = sany;
    __syncthreads();
    if (!any && tid == 255) { loc[7] = 1; lsum = 1; }
    int prev = (tid == 0) ? 1 : e[base - 1];
    if (!any && tid) prev = 0;
    int mk[8];
    int lmax = -1;
    #pragma unroll
    for (int i = 0; i < 8; ++i) {
        int pe = (i == 0) ? prev : loc[i - 1];
        if (i == 7 && !any && tid == 255) pe = e[base + 6];
        mk[i] = pe ? (base + i) : -1;
        lmax = max(lmax, mk[i]);
    }
    ssum[tid] = lsum; smax[tid] = lmax;
    __syncthreads();
    if (tid == 0) {
        int rs = 0, rm = -1;
        for (int i = 0; i < 256; ++i) {
            int ts = ssum[i], tm = smax[i];
            ssum[i] = rs; smax[i] = rm;
            rs += ts; rm = max(rm, tm);
        }
        stot = rs;
    }
    __syncthreads();
    int run = ssum[tid], rmax = smax[tid], tot = stot;
    int* cpb = cp + b*Ss;
    #pragma unroll
    for (int i = 0; i < 8; ++i) {
        int s = base + i;
        rmax = max(rmax, mk[i]);
        int chunk = run;
        run += loc[i];
        int pos = s - rmax;
        bool valid = (chunk < tot) && (chunk < MAXC) && (pos < MCL);
        cpb[s] = valid ? (chunk * MCL + pos) : -1;
    }
}

// ---------------- fill / scatter ----------------
__global__ void k_fill(float* __restrict__ out, const float* __restrict__ pad,
                       const int* __restrict__ padid) {
    int i = blockIdx.x * blockDim.x + threadIdx.x;
    constexpr int N4  = Bb * MAXC * MCL * D / 4;
    constexpr int NI4 = Bb * MAXC * MCL / 4;
    if (i < N4) {
        ((float4*)out)[i] = ((const float4*)pad)[i & 15];
    } else if (i < N4 + NI4) {
        float pv = (float)(*padid);
        float4 v; v.x = pv; v.y = pv; v.z = pv; v.w = pv;
        ((float4*)out)[i] = v;
    }
}

__global__ __launch_bounds__(256) void k_scatter(
    const float* __restrict__ X, const int* __restrict__ cp,
    const int* __restrict__ ids, float* __restrict__ out) {
    int tid = threadIdx.x;
    int w = tid >> 6, d = tid & 63;
    int t = blockIdx.x*4 + w;
    int c = cp[t];
    if (c < 0) return;
    int b = t >> 11;
    float* dst = out + ((size_t)(b * MAXC * MCL) + c) * D;
    dst[d] = X[t*D + d];
    if (d == 0)
        out[(size_t)Bb*MAXC*MCL*D + (size_t)b*MAXC*MCL + c] = (float)ids[t];
}

// ---------------- launch ----------------
extern "C" void kernel_launch(void* const* d_in, const int* in_sizes, int n_in,
                              void* d_out, int out_size, void* d_ws, size_t ws_size,
                              hipStream_t stream) {
    const float* x    = (const float*)d_in[0];
    const float* pad  = (const float*)d_in[1];
    const int*   xids = (const int*)  d_in[2];
    const int*   padid= (const int*)  d_in[3];
    const float* Wq   = (const float*)d_in[4];
    const float* Wk   = (const float*)d_in[5];
    const float* Wv   = (const float*)d_in[6];
    const float* Wo   = (const float*)d_in[7];
    const float* ln1  = (const float*)d_in[8];
    const float* ln2  = (const float*)d_in[9];
    const float* W1   = (const float*)d_in[10];
    const float* W2   = (const float*)d_in[11];
    const float* Wh   = (const float*)d_in[12];
    const float* bh   = (const float*)d_in[13];
    float* out = (float*)d_out;
    float* ws  = (float*)d_ws;

    float* X  = ws + WX;
    float* Qb = ws + WQ;
    float* KVb= ws + WKV;
    float* Ob = ws + WO;
    float* PBb= ws + WPB;
    float* Ub = ws + WU;
    float* L1b= ws + WL1;
    int*   EMb= (int*)(ws + WEM);
    int*   CPb= (int*)(ws + WCP);
    float* ct = ws + WCT;
    float* st = ws + WST;

    k_init<<<2048, 256, 0, stream>>>(x, X, ct, st);
    for (int l = 0; l < NL; ++l) {
        k_qkv <<<256, 256, 0, stream>>>(X, Wq + l*D*D, Wk + l*D*D, Wv + l*D*D,
                                        ln1 + l*D, ct, st, Qb, KVb);
        k_attn2<<<32*BPB, 256, 0, stream>>>(Qb, KVb, PBb);
        k_comb <<<32*16, 128, 0, stream>>>(PBb, Ob);
        k_post1<<<256, 256, 0, stream>>>(X, Ob, Wo + l*D*D);
        k_ffn1<<<NT/16, 256, 0, stream>>>(X, ln2 + l*D, W1 + l*D*FFNx, Ub);
        k_ffn2<<<NT/16, 256, 0, stream>>>(X, Ub, W2 + l*FFNx*D);
    }
    k_head<<<NT/4, 256, 0, stream>>>(X, Wh, bh, L1b, EMb);
    k_reg <<<1, 256, 0, stream>>>(L1b, out + (size_t)Bb*MAXC*MCL*D + Bb*MAXC*MCL);
    k_scan<<<Bb, 256, 0, stream>>>(EMb, CPb);
    k_fill<<<(Bb*MAXC*MCL*D/4 + Bb*MAXC*MCL/4 + 255)/256, 256, 0, stream>>>(out, pad, padid);
    k_scatter<<<NT/4, 256, 0, stream>>>(X, CPb, xids, out);
}

// Round 12
// 287.172 us; speedup vs baseline: 1.6875x; 1.1491x over previous
//
#include <hip/hip_runtime.h>
#include <math.h>

// ---------------- problem constants (fixed by setup_inputs) ----------------
constexpr int D   = 64;
constexpr int H   = 8;
constexpr int HD  = 8;
constexpr int NL  = 3;
constexpr int FFNx= 256;
constexpr int Bb  = 4;
constexpr int Ss  = 2048;
constexpr int NT  = Bb * Ss;        // 8192 tokens
constexpr int MAXC= 1024;
constexpr int MCL = 16;

// attention task decomposition: uniform tasks, chunk-major enumeration.
// Each task (128 q x 128 k) is computed by TWO waves (64 keys each) merged
// via LDS -> 8704 waves hide the in-order s_load latency; PB traffic same.
constexpr int QW   = 128;            // queries per task (2 per lane)
constexpr int CH   = 128;            // keys per task
constexpr int TPB  = 136;            // tasks per (b,h): sum_{s=0..15} (16-s)
constexpr int BPB  = 68;             // blocks per (b,h) (2 tasks per block)
constexpr int PBSZ = 1152;           // floats per partial: l(128) + o(1024)

// ---------------- workspace layout (float elements) ----------------
constexpr size_t WX  = 0;                        // [NT*D] = 524288
constexpr size_t WQ  = 524288;                   // [NT*D]
constexpr size_t WKV = 2621440;                  // [32*2048*16] interleaved K|V
constexpr size_t WO  = 3670016;                  // [NT*D]
constexpr size_t WPB = 4194304;                  // [32*TPB*PBSZ] attn partials
constexpr size_t WL1 = 9764864;                  // [NT]
constexpr size_t WEM = WL1 + NT;                 // [NT] int
constexpr size_t WCP = WEM + NT;                 // [NT] int
constexpr size_t WCT = WCP + NT;                 // [Ss*4]
constexpr size_t WST = WCT + Ss*4;               // [Ss*4]  (end ~9.81M floats)

constexpr float LOG2E = 1.4426950408889634f;

typedef float v2f  __attribute__((ext_vector_type(2)));
typedef float f16v __attribute__((ext_vector_type(16)));
// constant-address-space pointer: keys are wave-uniform & read-only inside
// k_attn2, so loads through this become s_load_dwordx16 (scalar pipe, SGPRs)
using ckv_t = const __attribute__((address_space(4))) f16v*;

__device__ __forceinline__ float rdlane(float v, int l) {
    return __builtin_bit_cast(float, __builtin_amdgcn_readlane(__builtin_bit_cast(int, v), l));
}

// ---------------- init: copy x -> X, build rope tables ----------------
__global__ void k_init(const float* __restrict__ x, float* __restrict__ X,
                       float* __restrict__ ct, float* __restrict__ st) {
    int i = blockIdx.x * blockDim.x + threadIdx.x;
    constexpr int N4 = NT * D / 4;
    if (i < N4) ((float4*)X)[i] = ((const float4*)x)[i];
    if (i < Ss * 4) {
        int s = i >> 2, f = i & 3;
        const float fr[4] = {1.0f, 0.1f, 0.01f, 0.001f};
        float ang = (float)s * fr[f];
        ct[i] = cosf(ang);
        st[i] = sinf(ang);
    }
}

// ---------------- rmsnorm + QKV + rope (wave-per-token, readlane bcast) ----
__global__ __launch_bounds__(256) void k_qkv(
    const float* __restrict__ X, const float* __restrict__ Wq,
    const float* __restrict__ Wk, const float* __restrict__ Wv,
    const float* __restrict__ g1, const float* __restrict__ ct,
    const float* __restrict__ st, float* __restrict__ Q,
    float* __restrict__ KV) {
    __shared__ float wq_s[D*D], wk_s[D*D], wv_s[D*D];
    __shared__ float g_s[D];
    int tid = threadIdx.x;
    for (int i = tid; i < D*D; i += 256) {
        wq_s[i] = Wq[i]; wk_s[i] = Wk[i]; wv_s[i] = Wv[i];
    }
    if (tid < D) g_s[tid] = g1[tid];
    __syncthreads();
    int w = tid >> 6, d = tid & 63;
    int t0 = blockIdx.x * 16;
    for (int it = 0; it < 4; ++it) {
        int t = t0 + it*4 + w;
        float xv = X[t*D + d];
        float ss = xv * xv;
        #pragma unroll
        for (int off = 32; off; off >>= 1) ss += __shfl_xor(ss, off);
        float r = 1.0f / sqrtf(ss * (1.0f/D) + 1e-6f);
        float h = xv * g_s[d] * r;
        float aq = 0.f, ak = 0.f, av = 0.f;
        #pragma unroll
        for (int j = 0; j < D; ++j) {
            float hj = rdlane(h, j);
            aq += hj * wq_s[j*D + d];
            ak += hj * wk_s[j*D + d];
            av += hj * wv_s[j*D + d];
        }
        int s  = t & (Ss - 1);
        int e  = d & 7;
        int fi = e & 3;
        float c  = ct[s*4 + fi];
        float sn = st[s*4 + fi];
        float pq = __shfl_xor(aq, 4);
        float pk = __shfl_xor(ak, 4);
        float rq, rk;
        if (e < 4) { rq = aq*c - pq*sn; rk = ak*c - pk*sn; }
        else       { rq = pq*sn + aq*c; rk = pk*sn + ak*c; }
        Q[t*D + d] = rq;
        int bq = t >> 11;
        int hh = d >> 3;
        float* kvp = KV + ((((size_t)(bq*H + hh))*Ss + s) << 4);
        kvp[e]     = rk;
        kvp[8 + e] = av;
    }
}

// ---------------- attention 64-key loop: s_load KV + packed-f32 math ------
template<bool DIAG>
__device__ __forceinline__ void attn_loop(
    ckv_t kvs, int L, int rel0,
    const v2f* __restrict__ q01, v2f& l01, v2f* __restrict__ oP) {
    #pragma unroll 4
    for (int j = 0; j < 64; ++j) {
        f16v kv = kvs[j];
        v2f acc;
        acc  = q01[0] * (v2f){kv[0], kv[0]};
        acc += q01[1] * (v2f){kv[1], kv[1]};
        acc += q01[2] * (v2f){kv[2], kv[2]};
        acc += q01[3] * (v2f){kv[3], kv[3]};
        acc += q01[4] * (v2f){kv[4], kv[4]};
        acc += q01[5] * (v2f){kv[5], kv[5]};
        acc += q01[6] * (v2f){kv[6], kv[6]};
        acc += q01[7] * (v2f){kv[7], kv[7]};
        if (DIAG) {
            int rel = rel0 + j;
            if (rel > L)      acc.x = -1e30f;
            if (rel > L + 64) acc.y = -1e30f;
        }
        v2f p;
        p.x = __builtin_amdgcn_exp2f(acc.x);
        p.y = __builtin_amdgcn_exp2f(acc.y);
        l01 += p;
        oP[0] += p * (v2f){kv[8],  kv[8]};
        oP[1] += p * (v2f){kv[9],  kv[9]};
        oP[2] += p * (v2f){kv[10], kv[10]};
        oP[3] += p * (v2f){kv[11], kv[11]};
        oP[4] += p * (v2f){kv[12], kv[12]};
        oP[5] += p * (v2f){kv[13], kv[13]};
        oP[6] += p * (v2f){kv[14], kv[14]};
        oP[7] += p * (v2f){kv[15], kv[15]};
    }
}

// ---------------- causal attention: paired-wave SMEM split, XCD-pinned ----
// blockIdx = xcd + 8*slot; bh = (slot/BPB)*8 + xcd. Block = 4 waves = 2
// tasks; pair waves {half 0,1} split a task's 128 keys and merge via LDS;
// even wave writes the combined partial (PB layout/traffic unchanged).
__global__ __launch_bounds__(256) void k_attn2(
    const float* __restrict__ Qg, const float* __restrict__ KV,
    float* __restrict__ PB) {
    __shared__ float comb[2][PBSZ];
    int xcd  = blockIdx.x & 7;
    int slot = blockIdx.x >> 3;
    int bhg  = slot / BPB;
    int blk  = slot - bhg * BPB;
    int bh   = bhg * 8 + xcd;
    int wvu  = __builtin_amdgcn_readfirstlane(threadIdx.x >> 6); // uniform
    int pair = wvu >> 1;
    int half = wvu & 1;
    int widb = blk * 2 + pair;                 // task 0..135 within bh
    int L = threadIdx.x & 63;
    int rem = widb;
    int s = 0;
    while (rem >= 16 - s) { rem -= 16 - s; ++s; }
    int t = s + rem;
    int b = bh >> 3, h = bh & 7;
    int qmin = t * QW;
    int k0 = s * CH + half * 64;

    const float SC = 0.35355339059327373f * LOG2E;   // 1/sqrt(8) * log2(e)
    const float* qp = Qg + ((size_t)(b*Ss + qmin + L))*D + h*HD;
    float4 qa0 = *(const float4*)(qp);
    float4 qb0 = *(const float4*)(qp + 4);
    float4 qa1 = *(const float4*)(qp + 64*D);
    float4 qb1 = *(const float4*)(qp + 64*D + 4);
    v2f q01[8];
    q01[0] = (v2f){qa0.x*SC, qa1.x*SC};
    q01[1] = (v2f){qa0.y*SC, qa1.y*SC};
    q01[2] = (v2f){qa0.z*SC, qa1.z*SC};
    q01[3] = (v2f){qa0.w*SC, qa1.w*SC};
    q01[4] = (v2f){qb0.x*SC, qb1.x*SC};
    q01[5] = (v2f){qb0.y*SC, qb1.y*SC};
    q01[6] = (v2f){qb0.z*SC, qb1.z*SC};
    q01[7] = (v2f){qb0.w*SC, qb1.w*SC};

    v2f l01 = (v2f){0.f, 0.f};
    v2f oP[8];
    #pragma unroll
    for (int e = 0; e < 8; ++e) oP[e] = (v2f){0.f, 0.f};

    ckv_t kvs = (ckv_t)(unsigned long long)(KV + (((size_t)bh*Ss + k0) << 4));
    if (s == t) attn_loop<true >(kvs, L, half*64, q01, l01, oP);
    else        attn_loop<false>(kvs, L, half*64, q01, l01, oP);

    if (half == 1) {
        comb[pair][L]      = l01.x;
        comb[pair][64 + L] = l01.y;
        #pragma unroll
        for (int e = 0; e < 8; ++e) {
            comb[pair][128 + e*128 + L]      = oP[e].x;
            comb[pair][128 + e*128 + 64 + L] = oP[e].y;
        }
    }
    __syncthreads();
    if (half == 0) {
        float* pb = PB + ((size_t)bh * TPB + widb) * PBSZ;
        pb[L]      = l01.x + comb[pair][L];
        pb[64 + L] = l01.y + comb[pair][64 + L];
        #pragma unroll
        for (int e = 0; e < 8; ++e) {
            pb[128 + e*128 + L]      = oP[e].x + comb[pair][128 + e*128 + L];
            pb[128 + e*128 + 64 + L] = oP[e].y + comb[pair][128 + e*128 + 64 + L];
        }
    }
}

// ---------------- combine partials -> O (plain sums, fixed bias) ----------
__global__ __launch_bounds__(128) void k_comb(const float* __restrict__ PB,
                                              float* __restrict__ Og) {
    int qs = threadIdx.x;           // 0..127
    int t  = blockIdx.x & 15;
    int bh = blockIdx.x >> 4;
    int b = bh >> 3, h = bh & 7;
    float Lx = 0.f;
    float O[8] = {0,0,0,0,0,0,0,0};
    for (int s3 = 0; s3 <= t; ++s3) {
        int idx = 16*s3 - (s3*(s3-1))/2 + (t - s3);
        const float* pb = PB + (size_t)(bh*TPB + idx) * PBSZ;
        Lx += pb[qs];
        #pragma unroll
        for (int e = 0; e < 8; ++e) O[e] += pb[128 + e*128 + qs];
    }
    float inv = 1.0f / Lx;
    float* op = Og + ((size_t)(b*Ss + t*QW + qs))*D + h*HD;
    #pragma unroll
    for (int e = 0; e < 8; ++e) op[e] = O[e] * inv;
}

// ---------------- x += O @ Wo (readlane bcast) ----------------
__global__ __launch_bounds__(256) void k_post1(
    float* __restrict__ X, const float* __restrict__ Og,
    const float* __restrict__ Wo) {
    __shared__ float ws_[D*D];
    int tid = threadIdx.x;
    for (int i = tid; i < D*D; i += 256) ws_[i] = Wo[i];
    __syncthreads();
    int w = tid >> 6, d = tid & 63;
    int t0 = blockIdx.x * 32;
    for (int it = 0; it < 8; ++it) {
        int t = t0 + it*4 + w;
        float ov = Og[t*D + d];
        float a = 0.f;
        #pragma unroll
        for (int j = 0; j < D; ++j) a += rdlane(ov, j) * ws_[j*D + d];
        X[t*D + d] += a;
    }
}

// ---------------- fused FFN: rms2 + W1 + gelu -> LDS -> W2, X += ---------
__global__ __launch_bounds__(256) void k_ffn(
    float* __restrict__ X, const float* __restrict__ g2,
    const float* __restrict__ W1, const float* __restrict__ W2) {
    __shared__ __align__(16) float h2t[64][20];   // [dim][token]
    __shared__ float part[16][16];
    __shared__ float g_s[D];
    __shared__ __align__(16) float ult[FFNx][20];  // [f][token]
    __shared__ float red[4][16][D];
    int tid = threadIdx.x;
    if (tid < D) g_s[tid] = g2[tid];
    int t0 = blockIdx.x * 16;
    int tk = tid >> 4, li = tid & 15;
    float x0 = X[(t0+tk)*D + li];
    float x1 = X[(t0+tk)*D + li + 16];
    float x2 = X[(t0+tk)*D + li + 32];
    float x3 = X[(t0+tk)*D + li + 48];
    part[tk][li] = x0*x0 + x1*x1 + x2*x2 + x3*x3;
    __syncthreads();
    if (tid < 16) {
        float s = 0.f;
        #pragma unroll
        for (int i = 0; i < 16; ++i) s += part[tid][i];
        part[tid][0] = 1.0f / sqrtf(s * (1.0f/D) + 1e-6f);
    }
    __syncthreads();
    float r = part[tk][0];
    h2t[li][tk]      = x0 * g_s[li]      * r;
    h2t[li + 16][tk] = x1 * g_s[li + 16] * r;
    h2t[li + 32][tk] = x2 * g_s[li + 32] * r;
    h2t[li + 48][tk] = x3 * g_s[li + 48] * r;
    __syncthreads();
    {   // phase 1: U = gelu(h2 @ W1), kept in LDS (ult[f][token])
        int f = tid;
        v2f acc2[8];
        #pragma unroll
        for (int i = 0; i < 8; ++i) acc2[i] = (v2f){0.f, 0.f};
        for (int j = 0; j < D; ++j) {
            float wv = W1[j*FFNx + f];
            v2f wv2 = (v2f){wv, wv};
            const float4* hp = (const float4*)&h2t[j][0];
            float4 a0 = hp[0], a1 = hp[1], a2 = hp[2], a3 = hp[3];
            const v2f* a0v = (const v2f*)&a0;
            const v2f* a1v = (const v2f*)&a1;
            const v2f* a2v = (const v2f*)&a2;
            const v2f* a3v = (const v2f*)&a3;
            acc2[0] += a0v[0]*wv2;  acc2[1] += a0v[1]*wv2;
            acc2[2] += a1v[0]*wv2;  acc2[3] += a1v[1]*wv2;
            acc2[4] += a2v[0]*wv2;  acc2[5] += a2v[1]*wv2;
            acc2[6] += a3v[0]*wv2;  acc2[7] += a3v[1]*wv2;
        }
        #pragma unroll
        for (int i = 0; i < 8; ++i) {
            float ua = acc2[i].x;
            float ub = acc2[i].y;
            ua = 0.5f * ua * (1.0f + erff(ua * 0.70710678118654752f));
            ub = 0.5f * ub * (1.0f + erff(ub * 0.70710678118654752f));
            ult[f][2*i]     = ua;
            ult[f][2*i + 1] = ub;
        }
    }
    __syncthreads();
    {   // phase 2: X += U @ W2
        int d = tid & 63, fp = tid >> 6;
        v2f acc2[8];
        #pragma unroll
        for (int i = 0; i < 8; ++i) acc2[i] = (v2f){0.f, 0.f};
        for (int fo = 0; fo < 64; ++fo) {
            int f = fp*64 + fo;
            float wv = W2[f*D + d];
            v2f wv2 = (v2f){wv, wv};
            const float4* up = (const float4*)&ult[f][0];
            float4 u0 = up[0], u1 = up[1], u2 = up[2], u3 = up[3];
            const v2f* u0v = (const v2f*)&u0;
            const v2f* u1v = (const v2f*)&u1;
            const v2f* u2v = (const v2f*)&u2;
            const v2f* u3v = (const v2f*)&u3;
            acc2[0] += u0v[0]*wv2;  acc2[1] += u0v[1]*wv2;
            acc2[2] += u1v[0]*wv2;  acc2[3] += u1v[1]*wv2;
            acc2[4] += u2v[0]*wv2;  acc2[5] += u2v[1]*wv2;
            acc2[6] += u3v[0]*wv2;  acc2[7] += u3v[1]*wv2;
        }
        #pragma unroll
        for (int i = 0; i < 8; ++i) {
            red[fp][2*i][d]     = acc2[i].x;
            red[fp][2*i + 1][d] = acc2[i].y;
        }
        __syncthreads();
        int tk2 = tid >> 6;
        #pragma unroll
        for (int k = 0; k < 4; ++k) {
            int tt = tk2 + k*4;
            float sum = red[0][tt][d] + red[1][tt][d] + red[2][tt][d] + red[3][tt][d];
            X[(t0 + tt)*D + d] += sum;
        }
    }
}

// ---------------- head ----------------
__global__ __launch_bounds__(256) void k_head(
    const float* __restrict__ X, const float* __restrict__ Wh,
    const float* __restrict__ bh, float* __restrict__ logit1,
    int* __restrict__ em) {
    int tid = threadIdx.x;
    int w = tid >> 6, d = tid & 63;
    int t = blockIdx.x*4 + w;
    float xv = X[t*D + d];
    float p0 = xv * Wh[d*2];
    float p1 = xv * Wh[d*2 + 1];
    #pragma unroll
    for (int off = 32; off; off >>= 1) {
        p0 += __shfl_xor(p0, off);
        p1 += __shfl_xor(p1, off);
    }
    if (d == 0) {
        float l0 = p0 + bh[0], l1 = p1 + bh[1];
        em[t] = (l0 > l1) ? 1 : 0;
        logit1[t] = l1;
    }
}

// ---------------- reg term ----------------
__global__ void k_reg(const float* __restrict__ logit1, float* __restrict__ outreg) {
    __shared__ float red[256];
    int tid = threadIdx.x;
    float s = 0.f;
    for (int i = tid; i < NT; i += 256) s += logit1[i];
    red[tid] = s;
    __syncthreads();
    for (int off = 128; off; off >>= 1) {
        if (tid < off) red[tid] += red[tid + off];
        __syncthreads();
    }
    if (tid == 0) *outreg = red[0] * (1.0f / NT);
}

// ---------------- per-batch scan ----------------
__global__ __launch_bounds__(256) void k_scan(const int* __restrict__ em,
                                              int* __restrict__ cp) {
    __shared__ int ssum[256], smax[256];
    __shared__ int sany, stot;
    int b = blockIdx.x, tid = threadIdx.x;
    const int* e = em + b*Ss;
    int base = tid * 8;
    int loc[8];
    int lsum = 0, lor = 0;
    #pragma unroll
    for (int i = 0; i < 8; ++i) { loc[i] = e[base + i]; lsum += loc[i]; lor |= loc[i]; }
    ssum[tid] = lor;
    __syncthreads();
    if (tid == 0) { int a = 0; for (int i = 0; i < 256; ++i) a |= ssum[i]; sany = a; }
    __syncthreads();
    int any = sany;
    __syncthreads();
    if (!any && tid == 255) { loc[7] = 1; lsum = 1; }
    int prev = (tid == 0) ? 1 : e[base - 1];
    if (!any && tid) prev = 0;
    int mk[8];
    int lmax = -1;
    #pragma unroll
    for (int i = 0; i < 8; ++i) {
        int pe = (i == 0) ? prev : loc[i - 1];
        if (i == 7 && !any && tid == 255) pe = e[base + 6];
        mk[i] = pe ? (base + i) : -1;
        lmax = max(lmax, mk[i]);
    }
    ssum[tid] = lsum; smax[tid] = lmax;
    __syncthreads();
    if (tid == 0) {
        int rs = 0, rm = -1;
        for (int i = 0; i < 256; ++i) {
            int ts = ssum[i], tm = smax[i];
            ssum[i] = rs; smax[i] = rm;
            rs += ts; rm = max(rm, tm);
        }
        stot = rs;
    }
    __syncthreads();
    int run = ssum[tid], rmax = smax[tid], tot = stot;
    int* cpb = cp + b*Ss;
    #pragma unroll
    for (int i = 0; i < 8; ++i) {
        int s = base + i;
        rmax = max(rmax, mk[i]);
        int chunk = run;
        run += loc[i];
        int pos = s - rmax;
        bool valid = (chunk < tot) && (chunk < MAXC) && (pos < MCL);
        cpb[s] = valid ? (chunk * MCL + pos) : -1;
    }
}

// ---------------- fill / scatter ----------------
__global__ void k_fill(float* __restrict__ out, const float* __restrict__ pad,
                       const int* __restrict__ padid) {
    int i = blockIdx.x * blockDim.x + threadIdx.x;
    constexpr int N4  = Bb * MAXC * MCL * D / 4;
    constexpr int NI4 = Bb * MAXC * MCL / 4;
    if (i < N4) {
        ((float4*)out)[i] = ((const float4*)pad)[i & 15];
    } else if (i < N4 + NI4) {
        float pv = (float)(*padid);
        float4 v; v.x = pv; v.y = pv; v.z = pv; v.w = pv;
        ((float4*)out)[i] = v;
    }
}

__global__ __launch_bounds__(256) void k_scatter(
    const float* __restrict__ X, const int* __restrict__ cp,
    const int* __restrict__ ids, float* __restrict__ out) {
    int tid = threadIdx.x;
    int w = tid >> 6, d = tid & 63;
    int t = blockIdx.x*4 + w;
    int c = cp[t];
    if (c < 0) return;
    int b = t >> 11;
    float* dst = out + ((size_t)(b * MAXC * MCL) + c) * D;
    dst[d] = X[t*D + d];
    if (d == 0)
        out[(size_t)Bb*MAXC*MCL*D + (size_t)b*MAXC*MCL + c] = (float)ids[t];
}

// ---------------- launch ----------------
extern "C" void kernel_launch(void* const* d_in, const int* in_sizes, int n_in,
                              void* d_out, int out_size, void* d_ws, size_t ws_size,
                              hipStream_t stream) {
    const float* x    = (const float*)d_in[0];
    const float* pad  = (const float*)d_in[1];
    const int*   xids = (const int*)  d_in[2];
    const int*   padid= (const int*)  d_in[3];
    const float* Wq   = (const float*)d_in[4];
    const float* Wk   = (const float*)d_in[5];
    const float* Wv   = (const float*)d_in[6];
    const float* Wo   = (const float*)d_in[7];
    const float* ln1  = (const float*)d_in[8];
    const float* ln2  = (const float*)d_in[9];
    const float* W1   = (const float*)d_in[10];
    const float* W2   = (const float*)d_in[11];
    const float* Wh   = (const float*)d_in[12];
    const float* bh   = (const float*)d_in[13];
    float* out = (float*)d_out;
    float* ws  = (float*)d_ws;

    float* X  = ws + WX;
    float* Qb = ws + WQ;
    float* KVb= ws + WKV;
    float* Ob = ws + WO;
    float* PBb= ws + WPB;
    float* L1b= ws + WL1;
    int*   EMb= (int*)(ws + WEM);
    int*   CPb= (int*)(ws + WCP);
    float* ct = ws + WCT;
    float* st = ws + WST;

    k_init<<<2048, 256, 0, stream>>>(x, X, ct, st);
    for (int l = 0; l < NL; ++l) {
        k_qkv <<<512, 256, 0, stream>>>(X, Wq + l*D*D, Wk + l*D*D, Wv + l*D*D,
                                        ln1 + l*D, ct, st, Qb, KVb);
        k_attn2<<<32*BPB, 256, 0, stream>>>(Qb, KVb, PBb);
        k_comb <<<32*16, 128, 0, stream>>>(PBb, Ob);
        k_post1<<<256, 256, 0, stream>>>(X, Ob, Wo + l*D*D);
        k_ffn  <<<NT/16, 256, 0, stream>>>(X, ln2 + l*D, W1 + l*D*FFNx, W2 + l*FFNx*D);
    }
    k_head<<<NT/4, 256, 0, stream>>>(X, Wh, bh, L1b, EMb);
    k_reg <<<1, 256, 0, stream>>>(L1b, out + (size_t)Bb*MAXC*MCL*D + Bb*MAXC*MCL);
    k_scan<<<Bb, 256, 0, stream>>>(EMb, CPb);
    k_fill<<<(Bb*MAXC*MCL*D/4 + Bb*MAXC*MCL/4 + 255)/256, 256, 0, stream>>>(out, pad, padid);
    k_scatter<<<NT/4, 256, 0, stream>>>(X, CPb, xids, out);
}

// Round 13
// 281.993 us; speedup vs baseline: 1.7185x; 1.0184x over previous
//
#include <hip/hip_runtime.h>
#include <math.h>

// ---------------- problem constants (fixed by setup_inputs) ----------------
constexpr int D   = 64;
constexpr int H   = 8;
constexpr int HD  = 8;
constexpr int NL  = 3;
constexpr int FFNx= 256;
constexpr int Bb  = 4;
constexpr int Ss  = 2048;
constexpr int NT  = Bb * Ss;        // 8192 tokens
constexpr int MAXC= 1024;
constexpr int MCL = 16;

// attention task decomposition (unchanged from round 12)
constexpr int QW   = 128;            // queries per task (2 per lane)
constexpr int CH   = 128;            // keys per task
constexpr int TPB  = 136;            // tasks per (b,h)
constexpr int BPB  = 68;             // blocks per (b,h) (2 tasks per block)
constexpr int PBSZ = 1152;           // floats per partial: l(128) + o(1024)

// ---------------- workspace layout (float elements) ----------------
constexpr size_t WX  = 0;                        // [NT*D]
constexpr size_t WQ  = 524288;                   // [NT*D]
constexpr size_t WKV = 2621440;                  // [32*2048*16] interleaved K|V
constexpr size_t WPB = 4194304;                  // [32*TPB*PBSZ] attn partials
constexpr size_t WL1 = 9764864;                  // [NT]
constexpr size_t WEM = WL1 + NT;                 // [NT] int
constexpr size_t WINV= WEM + NT;                 // [Bb*MAXC*MCL] int inverse map
constexpr size_t WCT = WINV + Bb*MAXC*MCL;       // [Ss*4]
constexpr size_t WST = WCT + Ss*4;               // [Ss*4]

constexpr float LOG2E = 1.4426950408889634f;

typedef float v2f  __attribute__((ext_vector_type(2)));
typedef float f16v __attribute__((ext_vector_type(16)));
using ckv_t = const __attribute__((address_space(4))) f16v*;

__device__ __forceinline__ float rdlane(float v, int l) {
    return __builtin_bit_cast(float, __builtin_amdgcn_readlane(__builtin_bit_cast(int, v), l));
}

// ---------------- init: copy x -> X, build rope tables ----------------
__global__ void k_init(const float* __restrict__ x, float* __restrict__ X,
                       float* __restrict__ ct, float* __restrict__ st) {
    int i = blockIdx.x * blockDim.x + threadIdx.x;
    constexpr int N4 = NT * D / 4;
    if (i < N4) ((float4*)X)[i] = ((const float4*)x)[i];
    if (i < Ss * 4) {
        int s = i >> 2, f = i & 3;
        const float fr[4] = {1.0f, 0.1f, 0.01f, 0.001f};
        float ang = (float)s * fr[f];
        ct[i] = cosf(ang);
        st[i] = sinf(ang);
    }
}

// ---------------- rmsnorm + QKV + rope (wave-per-token, readlane bcast) ----
__global__ __launch_bounds__(256) void k_qkv(
    const float* __restrict__ X, const float* __restrict__ Wq,
    const float* __restrict__ Wk, const float* __restrict__ Wv,
    const float* __restrict__ g1, const float* __restrict__ ct,
    const float* __restrict__ st, float* __restrict__ Q,
    float* __restrict__ KV) {
    __shared__ float wq_s[D*D], wk_s[D*D], wv_s[D*D];
    __shared__ float g_s[D];
    int tid = threadIdx.x;
    for (int i = tid; i < D*D; i += 256) {
        wq_s[i] = Wq[i]; wk_s[i] = Wk[i]; wv_s[i] = Wv[i];
    }
    if (tid < D) g_s[tid] = g1[tid];
    __syncthreads();
    int w = tid >> 6, d = tid & 63;
    int t0 = blockIdx.x * 16;
    for (int it = 0; it < 4; ++it) {
        int t = t0 + it*4 + w;
        float xv = X[t*D + d];
        float ss = xv * xv;
        #pragma unroll
        for (int off = 32; off; off >>= 1) ss += __shfl_xor(ss, off);
        float r = 1.0f / sqrtf(ss * (1.0f/D) + 1e-6f);
        float h = xv * g_s[d] * r;
        float aq = 0.f, ak = 0.f, av = 0.f;
        #pragma unroll
        for (int j = 0; j < D; ++j) {
            float hj = rdlane(h, j);
            aq += hj * wq_s[j*D + d];
            ak += hj * wk_s[j*D + d];
            av += hj * wv_s[j*D + d];
        }
        int s  = t & (Ss - 1);
        int e  = d & 7;
        int fi = e & 3;
        float c  = ct[s*4 + fi];
        float sn = st[s*4 + fi];
        float pq = __shfl_xor(aq, 4);
        float pk = __shfl_xor(ak, 4);
        float rq, rk;
        if (e < 4) { rq = aq*c - pq*sn; rk = ak*c - pk*sn; }
        else       { rq = pq*sn + aq*c; rk = pk*sn + ak*c; }
        Q[t*D + d] = rq;
        int bq = t >> 11;
        int hh = d >> 3;
        float* kvp = KV + ((((size_t)(bq*H + hh))*Ss + s) << 4);
        kvp[e]     = rk;
        kvp[8 + e] = av;
    }
}

// ---------------- attention 64-key loop: s_load KV + packed-f32 math ------
template<bool DIAG>
__device__ __forceinline__ void attn_loop(
    ckv_t kvs, int L, int rel0,
    const v2f* __restrict__ q01, v2f& l01, v2f* __restrict__ oP) {
    #pragma unroll 4
    for (int j = 0; j < 64; ++j) {
        f16v kv = kvs[j];
        v2f acc;
        acc  = q01[0] * (v2f){kv[0], kv[0]};
        acc += q01[1] * (v2f){kv[1], kv[1]};
        acc += q01[2] * (v2f){kv[2], kv[2]};
        acc += q01[3] * (v2f){kv[3], kv[3]};
        acc += q01[4] * (v2f){kv[4], kv[4]};
        acc += q01[5] * (v2f){kv[5], kv[5]};
        acc += q01[6] * (v2f){kv[6], kv[6]};
        acc += q01[7] * (v2f){kv[7], kv[7]};
        if (DIAG) {
            int rel = rel0 + j;
            if (rel > L)      acc.x = -1e30f;
            if (rel > L + 64) acc.y = -1e30f;
        }
        v2f p;
        p.x = __builtin_amdgcn_exp2f(acc.x);
        p.y = __builtin_amdgcn_exp2f(acc.y);
        l01 += p;
        oP[0] += p * (v2f){kv[8],  kv[8]};
        oP[1] += p * (v2f){kv[9],  kv[9]};
        oP[2] += p * (v2f){kv[10], kv[10]};
        oP[3] += p * (v2f){kv[11], kv[11]};
        oP[4] += p * (v2f){kv[12], kv[12]};
        oP[5] += p * (v2f){kv[13], kv[13]};
        oP[6] += p * (v2f){kv[14], kv[14]};
        oP[7] += p * (v2f){kv[15], kv[15]};
    }
}

// ---------------- causal attention: paired-wave SMEM split, XCD-pinned ----
__global__ __launch_bounds__(256) void k_attn2(
    const float* __restrict__ Qg, const float* __restrict__ KV,
    float* __restrict__ PB) {
    __shared__ float comb[2][PBSZ];
    int xcd  = blockIdx.x & 7;
    int slot = blockIdx.x >> 3;
    int bhg  = slot / BPB;
    int blk  = slot - bhg * BPB;
    int bh   = bhg * 8 + xcd;
    int wvu  = __builtin_amdgcn_readfirstlane(threadIdx.x >> 6); // uniform
    int pair = wvu >> 1;
    int half = wvu & 1;
    int widb = blk * 2 + pair;                 // task 0..135 within bh
    int L = threadIdx.x & 63;
    int rem = widb;
    int s = 0;
    while (rem >= 16 - s) { rem -= 16 - s; ++s; }
    int t = s + rem;
    int b = bh >> 3, h = bh & 7;
    int qmin = t * QW;
    int k0 = s * CH + half * 64;

    const float SC = 0.35355339059327373f * LOG2E;   // 1/sqrt(8) * log2(e)
    const float* qp = Qg + ((size_t)(b*Ss + qmin + L))*D + h*HD;
    float4 qa0 = *(const float4*)(qp);
    float4 qb0 = *(const float4*)(qp + 4);
    float4 qa1 = *(const float4*)(qp + 64*D);
    float4 qb1 = *(const float4*)(qp + 64*D + 4);
    v2f q01[8];
    q01[0] = (v2f){qa0.x*SC, qa1.x*SC};
    q01[1] = (v2f){qa0.y*SC, qa1.y*SC};
    q01[2] = (v2f){qa0.z*SC, qa1.z*SC};
    q01[3] = (v2f){qa0.w*SC, qa1.w*SC};
    q01[4] = (v2f){qb0.x*SC, qb1.x*SC};
    q01[5] = (v2f){qb0.y*SC, qb1.y*SC};
    q01[6] = (v2f){qb0.z*SC, qb1.z*SC};
    q01[7] = (v2f){qb0.w*SC, qb1.w*SC};

    v2f l01 = (v2f){0.f, 0.f};
    v2f oP[8];
    #pragma unroll
    for (int e = 0; e < 8; ++e) oP[e] = (v2f){0.f, 0.f};

    ckv_t kvs = (ckv_t)(unsigned long long)(KV + (((size_t)bh*Ss + k0) << 4));
    if (s == t) attn_loop<true >(kvs, L, half*64, q01, l01, oP);
    else        attn_loop<false>(kvs, L, half*64, q01, l01, oP);

    if (half == 1) {
        comb[pair][L]      = l01.x;
        comb[pair][64 + L] = l01.y;
        #pragma unroll
        for (int e = 0; e < 8; ++e) {
            comb[pair][128 + e*128 + L]      = oP[e].x;
            comb[pair][128 + e*128 + 64 + L] = oP[e].y;
        }
    }
    __syncthreads();
    if (half == 0) {
        float* pb = PB + ((size_t)bh * TPB + widb) * PBSZ;
        pb[L]      = l01.x + comb[pair][L];
        pb[64 + L] = l01.y + comb[pair][64 + L];
        #pragma unroll
        for (int e = 0; e < 8; ++e) {
            pb[128 + e*128 + L]      = oP[e].x + comb[pair][128 + e*128 + L];
            pb[128 + e*128 + 64 + L] = oP[e].y + comb[pair][128 + e*128 + 64 + L];
        }
    }
}

// ---------------- fused combine + X += O@Wo ----------------
// grid: (b,t,seg) = 4*16*4 = 256 blocks, 256 threads.
// Phase A: each thread combines partials for one (h, qs) -> oT LDS.
// Phase B: X += oT @ Wo (Wo in LDS, oT rows broadcast).
__global__ __launch_bounds__(256) void k_combo(
    const float* __restrict__ PB, float* __restrict__ X,
    const float* __restrict__ Wo) {
    __shared__ float wo_s[D*D];
    __shared__ float oT[32][65];
    int tid = threadIdx.x;
    int seg = blockIdx.x & 3;
    int t   = (blockIdx.x >> 2) & 15;
    int b   = blockIdx.x >> 6;
    for (int i = tid; i < D*D; i += 256) wo_s[i] = Wo[i];

    int h  = tid >> 5;             // 0..7
    int ql = tid & 31;             // 0..31
    int qs = seg*32 + ql;          // 0..127
    int bh = b*8 + h;
    float Lx = 0.f;
    float O[8] = {0,0,0,0,0,0,0,0};
    for (int s3 = 0; s3 <= t; ++s3) {
        int idx = 16*s3 - (s3*(s3-1))/2 + (t - s3);
        const float* pb = PB + (size_t)(bh*TPB + idx) * PBSZ;
        Lx += pb[qs];
        #pragma unroll
        for (int e = 0; e < 8; ++e) O[e] += pb[128 + e*128 + qs];
    }
    float inv = 1.0f / Lx;
    #pragma unroll
    for (int e = 0; e < 8; ++e) oT[ql][h*8 + e] = O[e] * inv;
    __syncthreads();

    int d = tid & 63, wv = tid >> 6;
    #pragma unroll 2
    for (int k = 0; k < 8; ++k) {
        int tt = wv*8 + k;           // 0..31
        float a = 0.f;
        #pragma unroll
        for (int j = 0; j < D; ++j) a += oT[tt][j] * wo_s[j*D + d];
        X[((size_t)(b*Ss) + t*128 + seg*32 + tt)*D + d] += a;
    }
}

// ---------------- fused FFN (+ optional head on last layer) ----------------
template<bool HEAD>
__global__ __launch_bounds__(256) void k_ffn(
    float* __restrict__ X, const float* __restrict__ g2,
    const float* __restrict__ W1, const float* __restrict__ W2,
    const float* __restrict__ Wh, const float* __restrict__ bhp,
    float* __restrict__ logit1, int* __restrict__ em) {
    __shared__ __align__(16) float h2t[64][20];   // [dim][token]
    __shared__ float part[16][16];
    __shared__ float g_s[D];
    __shared__ __align__(16) float ult[FFNx][20];  // [f][token]
    __shared__ float red[4][16][D];
    int tid = threadIdx.x;
    if (tid < D) g_s[tid] = g2[tid];
    int t0 = blockIdx.x * 16;
    int tk = tid >> 4, li = tid & 15;
    float x0 = X[(t0+tk)*D + li];
    float x1 = X[(t0+tk)*D + li + 16];
    float x2 = X[(t0+tk)*D + li + 32];
    float x3 = X[(t0+tk)*D + li + 48];
    part[tk][li] = x0*x0 + x1*x1 + x2*x2 + x3*x3;
    __syncthreads();
    if (tid < 16) {
        float s = 0.f;
        #pragma unroll
        for (int i = 0; i < 16; ++i) s += part[tid][i];
        part[tid][0] = 1.0f / sqrtf(s * (1.0f/D) + 1e-6f);
    }
    __syncthreads();
    float r = part[tk][0];
    h2t[li][tk]      = x0 * g_s[li]      * r;
    h2t[li + 16][tk] = x1 * g_s[li + 16] * r;
    h2t[li + 32][tk] = x2 * g_s[li + 32] * r;
    h2t[li + 48][tk] = x3 * g_s[li + 48] * r;
    __syncthreads();
    {   // phase 1: U = gelu(h2 @ W1) -> LDS
        int f = tid;
        v2f acc2[8];
        #pragma unroll
        for (int i = 0; i < 8; ++i) acc2[i] = (v2f){0.f, 0.f};
        for (int j = 0; j < D; ++j) {
            float wv = W1[j*FFNx + f];
            v2f wv2 = (v2f){wv, wv};
            const float4* hp = (const float4*)&h2t[j][0];
            float4 a0 = hp[0], a1 = hp[1], a2 = hp[2], a3 = hp[3];
            const v2f* a0v = (const v2f*)&a0;
            const v2f* a1v = (const v2f*)&a1;
            const v2f* a2v = (const v2f*)&a2;
            const v2f* a3v = (const v2f*)&a3;
            acc2[0] += a0v[0]*wv2;  acc2[1] += a0v[1]*wv2;
            acc2[2] += a1v[0]*wv2;  acc2[3] += a1v[1]*wv2;
            acc2[4] += a2v[0]*wv2;  acc2[5] += a2v[1]*wv2;
            acc2[6] += a3v[0]*wv2;  acc2[7] += a3v[1]*wv2;
        }
        #pragma unroll
        for (int i = 0; i < 8; ++i) {
            float ua = acc2[i].x;
            float ub = acc2[i].y;
            ua = 0.5f * ua * (1.0f + erff(ua * 0.70710678118654752f));
            ub = 0.5f * ub * (1.0f + erff(ub * 0.70710678118654752f));
            ult[f][2*i]     = ua;
            ult[f][2*i + 1] = ub;
        }
    }
    __syncthreads();
    {   // phase 2: X += U @ W2 (+ head on last layer)
        int d = tid & 63, fp = tid >> 6;
        v2f acc2[8];
        #pragma unroll
        for (int i = 0; i < 8; ++i) acc2[i] = (v2f){0.f, 0.f};
        for (int fo = 0; fo < 64; ++fo) {
            int f = fp*64 + fo;
            float wv = W2[f*D + d];
            v2f wv2 = (v2f){wv, wv};
            const float4* up = (const float4*)&ult[f][0];
            float4 u0 = up[0], u1 = up[1], u2 = up[2], u3 = up[3];
            const v2f* u0v = (const v2f*)&u0;
            const v2f* u1v = (const v2f*)&u1;
            const v2f* u2v = (const v2f*)&u2;
            const v2f* u3v = (const v2f*)&u3;
            acc2[0] += u0v[0]*wv2;  acc2[1] += u0v[1]*wv2;
            acc2[2] += u1v[0]*wv2;  acc2[3] += u1v[1]*wv2;
            acc2[4] += u2v[0]*wv2;  acc2[5] += u2v[1]*wv2;
            acc2[6] += u3v[0]*wv2;  acc2[7] += u3v[1]*wv2;
        }
        #pragma unroll
        for (int i = 0; i < 8; ++i) {
            red[fp][2*i][d]     = acc2[i].x;
            red[fp][2*i + 1][d] = acc2[i].y;
        }
        __syncthreads();
        int tk2 = tid >> 6;
        #pragma unroll
        for (int k = 0; k < 4; ++k) {
            int tt = tk2 + k*4;
            float sum = red[0][tt][d] + red[1][tt][d] + red[2][tt][d] + red[3][tt][d];
            float xf = X[(t0 + tt)*D + d] + sum;
            X[(t0 + tt)*D + d] = xf;
            if (HEAD) {
                float p0 = xf * Wh[d*2];
                float p1 = xf * Wh[d*2 + 1];
                #pragma unroll
                for (int off = 32; off; off >>= 1) {
                    p0 += __shfl_xor(p0, off);
                    p1 += __shfl_xor(p1, off);
                }
                if (d == 0) {
                    float l0 = p0 + bhp[0], l1 = p1 + bhp[1];
                    em[t0 + tt] = (l0 > l1) ? 1 : 0;
                    logit1[t0 + tt] = l1;
                }
            }
        }
    }
}

// ---------------- reg term ----------------
__global__ void k_reg(const float* __restrict__ logit1, float* __restrict__ outreg) {
    __shared__ float red[256];
    int tid = threadIdx.x;
    float s = 0.f;
    for (int i = tid; i < NT; i += 256) s += logit1[i];
    red[tid] = s;
    __syncthreads();
    for (int off = 128; off; off >>= 1) {
        if (tid < off) red[tid] += red[tid + off];
        __syncthreads();
    }
    if (tid == 0) *outreg = red[0] * (1.0f / NT);
}

// ---------------- per-batch scan -> inverse map ----------------
__global__ __launch_bounds__(256) void k_scan(const int* __restrict__ em,
                                              int* __restrict__ inv) {
    __shared__ int ssum[256], smax[256];
    __shared__ int sany, stot;
    int b = blockIdx.x, tid = threadIdx.x;
    int* invb = inv + b * (MAXC*MCL);
    for (int i = tid; i < MAXC*MCL; i += 256) invb[i] = -1;
    __syncthreads();
    const int* e = em + b*Ss;
    int base = tid * 8;
    int loc[8];
    int lsum = 0, lor = 0;
    #pragma unroll
    for (int i = 0; i < 8; ++i) { loc[i] = e[base + i]; lsum += loc[i]; lor |= loc[i]; }
    ssum[tid] = lor;
    __syncthreads();
    if (tid == 0) { int a = 0; for (int i = 0; i < 256; ++i) a |= ssum[i]; sany = a; }
    __syncthreads();
    int any = sany;
    __syncthreads();
    if (!any && tid == 255) { loc[7] = 1; lsum = 1; }
    int prev = (tid == 0) ? 1 : e[base - 1];
    if (!any && tid) prev = 0;
    int mk[8];
    int lmax = -1;
    #pragma unroll
    for (int i = 0; i < 8; ++i) {
        int pe = (i == 0) ? prev : loc[i - 1];
        if (i == 7 && !any && tid == 255) pe = e[base + 6];
        mk[i] = pe ? (base + i) : -1;
        lmax = max(lmax, mk[i]);
    }
    ssum[tid] = lsum; smax[tid] = lmax;
    __syncthreads();
    if (tid == 0) {
        int rs = 0, rm = -1;
        for (int i = 0; i < 256; ++i) {
            int ts = ssum[i], tm = smax[i];
            ssum[i] = rs; smax[i] = rm;
            rs += ts; rm = max(rm, tm);
        }
        stot = rs;
    }
    __syncthreads();
    int run = ssum[tid], rmax = smax[tid], tot = stot;
    #pragma unroll
    for (int i = 0; i < 8; ++i) {
        int s = base + i;
        rmax = max(rmax, mk[i]);
        int chunk = run;
        run += loc[i];
        int pos = s - rmax;
        bool valid = (chunk < tot) && (chunk < MAXC) && (pos < MCL);
        if (valid) invb[chunk * MCL + pos] = b*Ss + s;   // global token id
    }
}

// ---------------- gather epilogue: write out (vectors + ids) --------------
__global__ __launch_bounds__(256) void k_out(
    const float* __restrict__ X, const float* __restrict__ pad,
    const int* __restrict__ xids, const int* __restrict__ padid,
    const int* __restrict__ inv, float* __restrict__ out) {
    int i = blockIdx.x * blockDim.x + threadIdx.x;
    constexpr int NV4 = Bb * MAXC * MCL * D / 4;   // 1048576
    constexpr int NI4 = Bb * MAXC * MCL / 4;       // 16384
    if (i < NV4) {
        int slot = i >> 4;
        int d4 = i & 15;
        int t = inv[slot];
        float4 v = (t >= 0) ? ((const float4*)X)[t*16 + d4]
                            : ((const float4*)pad)[d4];
        ((float4*)out)[i] = v;
    } else if (i < NV4 + NI4) {
        int j = i - NV4;
        float pv = (float)(*padid);
        int base = j * 4;
        int t0_ = inv[base], t1_ = inv[base+1], t2_ = inv[base+2], t3_ = inv[base+3];
        float4 v;
        v.x = (t0_ >= 0) ? (float)xids[t0_] : pv;
        v.y = (t1_ >= 0) ? (float)xids[t1_] : pv;
        v.z = (t2_ >= 0) ? (float)xids[t2_] : pv;
        v.w = (t3_ >= 0) ? (float)xids[t3_] : pv;
        ((float4*)out)[i] = v;
    }
}

// ---------------- launch ----------------
extern "C" void kernel_launch(void* const* d_in, const int* in_sizes, int n_in,
                              void* d_out, int out_size, void* d_ws, size_t ws_size,
                              hipStream_t stream) {
    const float* x    = (const float*)d_in[0];
    const float* pad  = (const float*)d_in[1];
    const int*   xids = (const int*)  d_in[2];
    const int*   padid= (const int*)  d_in[3];
    const float* Wq   = (const float*)d_in[4];
    const float* Wk   = (const float*)d_in[5];
    const float* Wv   = (const float*)d_in[6];
    const float* Wo   = (const float*)d_in[7];
    const float* ln1  = (const float*)d_in[8];
    const float* ln2  = (const float*)d_in[9];
    const float* W1   = (const float*)d_in[10];
    const float* W2   = (const float*)d_in[11];
    const float* Wh   = (const float*)d_in[12];
    const float* bh   = (const float*)d_in[13];
    float* out = (float*)d_out;
    float* ws  = (float*)d_ws;

    float* X  = ws + WX;
    float* Qb = ws + WQ;
    float* KVb= ws + WKV;
    float* PBb= ws + WPB;
    float* L1b= ws + WL1;
    int*   EMb= (int*)(ws + WEM);
    int*   INVb=(int*)(ws + WINV);
    float* ct = ws + WCT;
    float* st = ws + WST;

    k_init<<<2048, 256, 0, stream>>>(x, X, ct, st);
    for (int l = 0; l < NL; ++l) {
        k_qkv <<<512, 256, 0, stream>>>(X, Wq + l*D*D, Wk + l*D*D, Wv + l*D*D,
                                        ln1 + l*D, ct, st, Qb, KVb);
        k_attn2<<<32*BPB, 256, 0, stream>>>(Qb, KVb, PBb);
        k_combo<<<256, 256, 0, stream>>>(PBb, X, Wo + l*D*D);
        if (l == NL - 1)
            k_ffn<true ><<<NT/16, 256, 0, stream>>>(X, ln2 + l*D, W1 + l*D*FFNx,
                                                    W2 + l*FFNx*D, Wh, bh, L1b, EMb);
        else
            k_ffn<false><<<NT/16, 256, 0, stream>>>(X, ln2 + l*D, W1 + l*D*FFNx,
                                                    W2 + l*FFNx*D, nullptr, nullptr,
                                                    nullptr, nullptr);
    }
    k_reg <<<1, 256, 0, stream>>>(L1b, out + (size_t)Bb*MAXC*MCL*D + Bb*MAXC*MCL);
    k_scan<<<Bb, 256, 0, stream>>>(EMb, INVb);
    k_out <<<(Bb*MAXC*MCL*D/4 + Bb*MAXC*MCL/4 + 255)/256, 256, 0, stream>>>(
        X, pad, xids, padid, INVb, out);
}

// Round 14
// 281.803 us; speedup vs baseline: 1.7197x; 1.0007x over previous
//
#include <hip/hip_runtime.h>
#include <math.h>

// ---------------- problem constants (fixed by setup_inputs) ----------------
constexpr int D   = 64;
constexpr int H   = 8;
constexpr int HD  = 8;
constexpr int NL  = 3;
constexpr int FFNx= 256;
constexpr int Bb  = 4;
constexpr int Ss  = 2048;
constexpr int NT  = Bb * Ss;        // 8192 tokens
constexpr int MAXC= 1024;
constexpr int MCL = 16;

// attention: q-tile = 256 (4 queries/lane), key chunk = 128 (paired waves
// of 64 keys). tasks per bh: sum_{t=0..7} 2(t+1) = 72; canonical task index
// = t*(t+1) + s  (s in 0..2t+1). Enumeration for dispatch is s-outer.
constexpr int TPB  = 72;             // tasks per (b,h)
constexpr int BPB  = 36;             // blocks per (b,h) (2 tasks per block)
constexpr int PBSZ = 2304;           // floats per partial: l(256) + o(2048)

// ---------------- workspace layout (float elements) ----------------
constexpr size_t WX  = 0;                        // [NT*D]
constexpr size_t WQ  = 524288;                   // [NT*D]
constexpr size_t WKV = 2621440;                  // [32*2048*16] interleaved K|V
constexpr size_t WPB = 4194304;                  // [32*TPB*PBSZ] attn partials
constexpr size_t WL1 = 9764864;                  // [NT]
constexpr size_t WEM = WL1 + NT;                 // [NT] int
constexpr size_t WINV= WEM + NT;                 // [Bb*MAXC*MCL] int inverse map
constexpr size_t WCT = WINV + Bb*MAXC*MCL;       // [Ss*4]
constexpr size_t WST = WCT + Ss*4;               // [Ss*4]

constexpr float LOG2E = 1.4426950408889634f;

typedef float v2f  __attribute__((ext_vector_type(2)));
typedef float f16v __attribute__((ext_vector_type(16)));
using ckv_t = const __attribute__((address_space(4))) f16v*;

__device__ __forceinline__ float rdlane(float v, int l) {
    return __builtin_bit_cast(float, __builtin_amdgcn_readlane(__builtin_bit_cast(int, v), l));
}

// ---------------- init: copy x -> X, build rope tables ----------------
__global__ void k_init(const float* __restrict__ x, float* __restrict__ X,
                       float* __restrict__ ct, float* __restrict__ st) {
    int i = blockIdx.x * blockDim.x + threadIdx.x;
    constexpr int N4 = NT * D / 4;
    if (i < N4) ((float4*)X)[i] = ((const float4*)x)[i];
    if (i < Ss * 4) {
        int s = i >> 2, f = i & 3;
        const float fr[4] = {1.0f, 0.1f, 0.01f, 0.001f};
        float ang = (float)s * fr[f];
        ct[i] = cosf(ang);
        st[i] = sinf(ang);
    }
}

// ---------------- rmsnorm + QKV + rope (wave-per-token, readlane bcast) ----
__global__ __launch_bounds__(256) void k_qkv(
    const float* __restrict__ X, const float* __restrict__ Wq,
    const float* __restrict__ Wk, const float* __restrict__ Wv,
    const float* __restrict__ g1, const float* __restrict__ ct,
    const float* __restrict__ st, float* __restrict__ Q,
    float* __restrict__ KV) {
    __shared__ float wq_s[D*D], wk_s[D*D], wv_s[D*D];
    __shared__ float g_s[D];
    int tid = threadIdx.x;
    for (int i = tid; i < D*D; i += 256) {
        wq_s[i] = Wq[i]; wk_s[i] = Wk[i]; wv_s[i] = Wv[i];
    }
    if (tid < D) g_s[tid] = g1[tid];
    __syncthreads();
    int w = tid >> 6, d = tid & 63;
    int t0 = blockIdx.x * 16;
    for (int it = 0; it < 4; ++it) {
        int t = t0 + it*4 + w;
        float xv = X[t*D + d];
        float ss = xv * xv;
        #pragma unroll
        for (int off = 32; off; off >>= 1) ss += __shfl_xor(ss, off);
        float r = 1.0f / sqrtf(ss * (1.0f/D) + 1e-6f);
        float h = xv * g_s[d] * r;
        float aq = 0.f, ak = 0.f, av = 0.f;
        #pragma unroll
        for (int j = 0; j < D; ++j) {
            float hj = rdlane(h, j);
            aq += hj * wq_s[j*D + d];
            ak += hj * wk_s[j*D + d];
            av += hj * wv_s[j*D + d];
        }
        int s  = t & (Ss - 1);
        int e  = d & 7;
        int fi = e & 3;
        float c  = ct[s*4 + fi];
        float sn = st[s*4 + fi];
        float pq = __shfl_xor(aq, 4);
        float pk = __shfl_xor(ak, 4);
        float rq, rk;
        if (e < 4) { rq = aq*c - pq*sn; rk = ak*c - pk*sn; }
        else       { rq = pq*sn + aq*c; rk = pk*sn + ak*c; }
        Q[t*D + d] = rq;
        int bq = t >> 11;
        int hh = d >> 3;
        float* kvp = KV + ((((size_t)(bq*H + hh))*Ss + s) << 4);
        kvp[e]     = rk;
        kvp[8 + e] = av;
    }
}

// ---------------- attention 64-key loop: 4 queries/lane, s_load KV --------
// DIAG: 0 = no mask; 1 = chunk s==2t (mask pair0: q0 vs rel>L, q1 vs
// rel>64+L; pair1 unmasked); 2 = chunk s==2t+1 (pair0 fully masked ->
// skipped, pair1 masked like std).
template<int DIAG>
__device__ __forceinline__ void attn_loop4(
    ckv_t kvs, int L, int rel0,
    const v2f* __restrict__ qp0, const v2f* __restrict__ qp1,
    v2f& l0, v2f& l1, v2f* __restrict__ o0, v2f* __restrict__ o1) {
    #pragma unroll 4
    for (int j = 0; j < 64; ++j) {
        f16v kv = kvs[j];
        v2f a1;
        a1  = qp1[0] * (v2f){kv[0], kv[0]};
        a1 += qp1[1] * (v2f){kv[1], kv[1]};
        a1 += qp1[2] * (v2f){kv[2], kv[2]};
        a1 += qp1[3] * (v2f){kv[3], kv[3]};
        a1 += qp1[4] * (v2f){kv[4], kv[4]};
        a1 += qp1[5] * (v2f){kv[5], kv[5]};
        a1 += qp1[6] * (v2f){kv[6], kv[6]};
        a1 += qp1[7] * (v2f){kv[7], kv[7]};
        if (DIAG == 2) {
            int rel = rel0 + j;
            if (rel > L)      a1.x = -1e30f;
            if (rel > L + 64) a1.y = -1e30f;
        }
        v2f p1;
        p1.x = __builtin_amdgcn_exp2f(a1.x);
        p1.y = __builtin_amdgcn_exp2f(a1.y);
        l1 += p1;
        o1[0] += p1 * (v2f){kv[8],  kv[8]};
        o1[1] += p1 * (v2f){kv[9],  kv[9]};
        o1[2] += p1 * (v2f){kv[10], kv[10]};
        o1[3] += p1 * (v2f){kv[11], kv[11]};
        o1[4] += p1 * (v2f){kv[12], kv[12]};
        o1[5] += p1 * (v2f){kv[13], kv[13]};
        o1[6] += p1 * (v2f){kv[14], kv[14]};
        o1[7] += p1 * (v2f){kv[15], kv[15]};
        if (DIAG != 2) {
            v2f a0;
            a0  = qp0[0] * (v2f){kv[0], kv[0]};
            a0 += qp0[1] * (v2f){kv[1], kv[1]};
            a0 += qp0[2] * (v2f){kv[2], kv[2]};
            a0 += qp0[3] * (v2f){kv[3], kv[3]};
            a0 += qp0[4] * (v2f){kv[4], kv[4]};
            a0 += qp0[5] * (v2f){kv[5], kv[5]};
            a0 += qp0[6] * (v2f){kv[6], kv[6]};
            a0 += qp0[7] * (v2f){kv[7], kv[7]};
            if (DIAG == 1) {
                int rel = rel0 + j;
                if (rel > L)      a0.x = -1e30f;
                if (rel > L + 64) a0.y = -1e30f;
            }
            v2f p0;
            p0.x = __builtin_amdgcn_exp2f(a0.x);
            p0.y = __builtin_amdgcn_exp2f(a0.y);
            l0 += p0;
            o0[0] += p0 * (v2f){kv[8],  kv[8]};
            o0[1] += p0 * (v2f){kv[9],  kv[9]};
            o0[2] += p0 * (v2f){kv[10], kv[10]};
            o0[3] += p0 * (v2f){kv[11], kv[11]};
            o0[4] += p0 * (v2f){kv[12], kv[12]};
            o0[5] += p0 * (v2f){kv[13], kv[13]};
            o0[6] += p0 * (v2f){kv[14], kv[14]};
            o0[7] += p0 * (v2f){kv[15], kv[15]};
        }
    }
}

// ---------------- causal attention: 4 q/lane, paired-wave, XCD-pinned -----
// blockIdx = xcd + 8*slot; bh = (slot/BPB)*8 + xcd. Block = 4 waves = 2
// tasks; pair waves {half 0,1} split a chunk's 128 keys and merge via LDS.
// Task enumeration s-outer (chunk s shared across t >= s/2 for locality);
// PB indexed canonically by t*(t+1)+s. Bitwise-identical sums to round 13.
__global__ __launch_bounds__(256) void k_attn2(
    const float* __restrict__ Qg, const float* __restrict__ KV,
    float* __restrict__ PB) {
    __shared__ float comb[2][PBSZ];
    int xcd  = blockIdx.x & 7;
    int slot = blockIdx.x >> 3;
    int bhg  = slot / BPB;
    int blk  = slot - bhg * BPB;
    int bh   = bhg * 8 + xcd;
    int wvu  = __builtin_amdgcn_readfirstlane(threadIdx.x >> 6); // uniform
    int pair = wvu >> 1;
    int half = wvu & 1;
    int widb = blk * 2 + pair;                 // task 0..71 (s-outer order)
    int L = threadIdx.x & 63;
    int rem = widb;
    int s = 0;
    while (rem >= 8 - (s >> 1)) { rem -= 8 - (s >> 1); ++s; }
    int t = (s >> 1) + rem;
    int b = bh >> 3, h = bh & 7;
    int qmin = t * 256;
    int k0 = s * 128 + half * 64;

    const float SC = 0.35355339059327373f * LOG2E;   // 1/sqrt(8) * log2(e)
    const float* qp = Qg + ((size_t)(b*Ss + qmin + L))*D + h*HD;
    float4 qa0 = *(const float4*)(qp);
    float4 qb0 = *(const float4*)(qp + 4);
    float4 qa1 = *(const float4*)(qp + 64*D);
    float4 qb1 = *(const float4*)(qp + 64*D + 4);
    float4 qa2 = *(const float4*)(qp + 128*D);
    float4 qb2 = *(const float4*)(qp + 128*D + 4);
    float4 qa3 = *(const float4*)(qp + 192*D);
    float4 qb3 = *(const float4*)(qp + 192*D + 4);
    v2f qp0[8], qp1[8];
    qp0[0] = (v2f){qa0.x*SC, qa1.x*SC};  qp1[0] = (v2f){qa2.x*SC, qa3.x*SC};
    qp0[1] = (v2f){qa0.y*SC, qa1.y*SC};  qp1[1] = (v2f){qa2.y*SC, qa3.y*SC};
    qp0[2] = (v2f){qa0.z*SC, qa1.z*SC};  qp1[2] = (v2f){qa2.z*SC, qa3.z*SC};
    qp0[3] = (v2f){qa0.w*SC, qa1.w*SC};  qp1[3] = (v2f){qa2.w*SC, qa3.w*SC};
    qp0[4] = (v2f){qb0.x*SC, qb1.x*SC};  qp1[4] = (v2f){qb2.x*SC, qb3.x*SC};
    qp0[5] = (v2f){qb0.y*SC, qb1.y*SC};  qp1[5] = (v2f){qb2.y*SC, qb3.y*SC};
    qp0[6] = (v2f){qb0.z*SC, qb1.z*SC};  qp1[6] = (v2f){qb2.z*SC, qb3.z*SC};
    qp0[7] = (v2f){qb0.w*SC, qb1.w*SC};  qp1[7] = (v2f){qb2.w*SC, qb3.w*SC};

    v2f l0 = (v2f){0.f, 0.f}, l1 = (v2f){0.f, 0.f};
    v2f o0[8], o1[8];
    #pragma unroll
    for (int e = 0; e < 8; ++e) { o0[e] = (v2f){0.f, 0.f}; o1[e] = (v2f){0.f, 0.f}; }

    ckv_t kvs = (ckv_t)(unsigned long long)(KV + (((size_t)bh*Ss + k0) << 4));
    if (s == 2*t)          attn_loop4<1>(kvs, L, half*64, qp0, qp1, l0, l1, o0, o1);
    else if (s == 2*t + 1) attn_loop4<2>(kvs, L, half*64, qp0, qp1, l0, l1, o0, o1);
    else                   attn_loop4<0>(kvs, L, half*64, qp0, qp1, l0, l1, o0, o1);

    if (half == 1) {
        comb[pair][L]       = l0.x;
        comb[pair][64 + L]  = l0.y;
        comb[pair][128 + L] = l1.x;
        comb[pair][192 + L] = l1.y;
        #pragma unroll
        for (int e = 0; e < 8; ++e) {
            comb[pair][256 + e*256 + L]       = o0[e].x;
            comb[pair][256 + e*256 + 64 + L]  = o0[e].y;
            comb[pair][256 + e*256 + 128 + L] = o1[e].x;
            comb[pair][256 + e*256 + 192 + L] = o1[e].y;
        }
    }
    __syncthreads();
    if (half == 0) {
        int pbidx = t*(t+1) + s;
        float* pb = PB + ((size_t)bh * TPB + pbidx) * PBSZ;
        pb[L]       = l0.x + comb[pair][L];
        pb[64 + L]  = l0.y + comb[pair][64 + L];
        pb[128 + L] = l1.x + comb[pair][128 + L];
        pb[192 + L] = l1.y + comb[pair][192 + L];
        #pragma unroll
        for (int e = 0; e < 8; ++e) {
            pb[256 + e*256 + L]       = o0[e].x + comb[pair][256 + e*256 + L];
            pb[256 + e*256 + 64 + L]  = o0[e].y + comb[pair][256 + e*256 + 64 + L];
            pb[256 + e*256 + 128 + L] = o1[e].x + comb[pair][256 + e*256 + 128 + L];
            pb[256 + e*256 + 192 + L] = o1[e].y + comb[pair][256 + e*256 + 192 + L];
        }
    }
}

// ---------------- fused combine + X += O@Wo ----------------
// grid: (b, t in 0..7, seg in 0..7) = 256 blocks, 256 threads.
__global__ __launch_bounds__(256) void k_combo(
    const float* __restrict__ PB, float* __restrict__ X,
    const float* __restrict__ Wo) {
    __shared__ float wo_s[D*D];
    __shared__ float oT[32][65];
    int tid = threadIdx.x;
    int seg = blockIdx.x & 7;
    int t   = (blockIdx.x >> 3) & 7;
    int b   = blockIdx.x >> 6;
    for (int i = tid; i < D*D; i += 256) wo_s[i] = Wo[i];

    int h  = tid >> 5;             // 0..7
    int ql = tid & 31;             // 0..31
    int qs = seg*32 + ql;          // 0..255
    int bh = b*8 + h;
    int nch = 2*(t+1);
    float Lx = 0.f;
    float O[8] = {0,0,0,0,0,0,0,0};
    for (int s3 = 0; s3 < nch; ++s3) {
        int idx = t*(t+1) + s3;
        const float* pb = PB + (size_t)(bh*TPB + idx) * PBSZ;
        Lx += pb[qs];
        #pragma unroll
        for (int e = 0; e < 8; ++e) O[e] += pb[256 + e*256 + qs];
    }
    float inv = 1.0f / Lx;
    #pragma unroll
    for (int e = 0; e < 8; ++e) oT[ql][h*8 + e] = O[e] * inv;
    __syncthreads();

    int d = tid & 63, wv = tid >> 6;
    #pragma unroll 2
    for (int k = 0; k < 8; ++k) {
        int tt = wv*8 + k;           // 0..31
        float a = 0.f;
        #pragma unroll
        for (int j = 0; j < D; ++j) a += oT[tt][j] * wo_s[j*D + d];
        X[((size_t)(b*Ss) + t*256 + seg*32 + tt)*D + d] += a;
    }
}

// ---------------- fused FFN (+ optional head on last layer) ----------------
template<bool HEAD>
__global__ __launch_bounds__(256) void k_ffn(
    float* __restrict__ X, const float* __restrict__ g2,
    const float* __restrict__ W1, const float* __restrict__ W2,
    const float* __restrict__ Wh, const float* __restrict__ bhp,
    float* __restrict__ logit1, int* __restrict__ em) {
    __shared__ __align__(16) float h2t[64][20];   // [dim][token]
    __shared__ float part[16][16];
    __shared__ float g_s[D];
    __shared__ __align__(16) float ult[FFNx][20];  // [f][token]
    __shared__ float red[4][16][D];
    int tid = threadIdx.x;
    if (tid < D) g_s[tid] = g2[tid];
    int t0 = blockIdx.x * 16;
    int tk = tid >> 4, li = tid & 15;
    float x0 = X[(t0+tk)*D + li];
    float x1 = X[(t0+tk)*D + li + 16];
    float x2 = X[(t0+tk)*D + li + 32];
    float x3 = X[(t0+tk)*D + li + 48];
    part[tk][li] = x0*x0 + x1*x1 + x2*x2 + x3*x3;
    __syncthreads();
    if (tid < 16) {
        float s = 0.f;
        #pragma unroll
        for (int i = 0; i < 16; ++i) s += part[tid][i];
        part[tid][0] = 1.0f / sqrtf(s * (1.0f/D) + 1e-6f);
    }
    __syncthreads();
    float r = part[tk][0];
    h2t[li][tk]      = x0 * g_s[li]      * r;
    h2t[li + 16][tk] = x1 * g_s[li + 16] * r;
    h2t[li + 32][tk] = x2 * g_s[li + 32] * r;
    h2t[li + 48][tk] = x3 * g_s[li + 48] * r;
    __syncthreads();
    {   // phase 1: U = gelu(h2 @ W1) -> LDS
        int f = tid;
        v2f acc2[8];
        #pragma unroll
        for (int i = 0; i < 8; ++i) acc2[i] = (v2f){0.f, 0.f};
        for (int j = 0; j < D; ++j) {
            float wv = W1[j*FFNx + f];
            v2f wv2 = (v2f){wv, wv};
            const float4* hp = (const float4*)&h2t[j][0];
            float4 a0 = hp[0], a1 = hp[1], a2 = hp[2], a3 = hp[3];
            const v2f* a0v = (const v2f*)&a0;
            const v2f* a1v = (const v2f*)&a1;
            const v2f* a2v = (const v2f*)&a2;
            const v2f* a3v = (const v2f*)&a3;
            acc2[0] += a0v[0]*wv2;  acc2[1] += a0v[1]*wv2;
            acc2[2] += a1v[0]*wv2;  acc2[3] += a1v[1]*wv2;
            acc2[4] += a2v[0]*wv2;  acc2[5] += a2v[1]*wv2;
            acc2[6] += a3v[0]*wv2;  acc2[7] += a3v[1]*wv2;
        }
        #pragma unroll
        for (int i = 0; i < 8; ++i) {
            float ua = acc2[i].x;
            float ub = acc2[i].y;
            ua = 0.5f * ua * (1.0f + erff(ua * 0.70710678118654752f));
            ub = 0.5f * ub * (1.0f + erff(ub * 0.70710678118654752f));
            ult[f][2*i]     = ua;
            ult[f][2*i + 1] = ub;
        }
    }
    __syncthreads();
    {   // phase 2: X += U @ W2 (+ head on last layer)
        int d = tid & 63, fp = tid >> 6;
        v2f acc2[8];
        #pragma unroll
        for (int i = 0; i < 8; ++i) acc2[i] = (v2f){0.f, 0.f};
        for (int fo = 0; fo < 64; ++fo) {
            int f = fp*64 + fo;
            float wv = W2[f*D + d];
            v2f wv2 = (v2f){wv, wv};
            const float4* up = (const float4*)&ult[f][0];
            float4 u0 = up[0], u1 = up[1], u2 = up[2], u3 = up[3];
            const v2f* u0v = (const v2f*)&u0;
            const v2f* u1v = (const v2f*)&u1;
            const v2f* u2v = (const v2f*)&u2;
            const v2f* u3v = (const v2f*)&u3;
            acc2[0] += u0v[0]*wv2;  acc2[1] += u0v[1]*wv2;
            acc2[2] += u1v[0]*wv2;  acc2[3] += u1v[1]*wv2;
            acc2[4] += u2v[0]*wv2;  acc2[5] += u2v[1]*wv2;
            acc2[6] += u3v[0]*wv2;  acc2[7] += u3v[1]*wv2;
        }
        #pragma unroll
        for (int i = 0; i < 8; ++i) {
            red[fp][2*i][d]     = acc2[i].x;
            red[fp][2*i + 1][d] = acc2[i].y;
        }
        __syncthreads();
        int tk2 = tid >> 6;
        #pragma unroll
        for (int k = 0; k < 4; ++k) {
            int tt = tk2 + k*4;
            float sum = red[0][tt][d] + red[1][tt][d] + red[2][tt][d] + red[3][tt][d];
            float xf = X[(t0 + tt)*D + d] + sum;
            X[(t0 + tt)*D + d] = xf;
            if (HEAD) {
                float p0 = xf * Wh[d*2];
                float p1 = xf * Wh[d*2 + 1];
                #pragma unroll
                for (int off = 32; off; off >>= 1) {
                    p0 += __shfl_xor(p0, off);
                    p1 += __shfl_xor(p1, off);
                }
                if (d == 0) {
                    float l0 = p0 + bhp[0], l1 = p1 + bhp[1];
                    em[t0 + tt] = (l0 > l1) ? 1 : 0;
                    logit1[t0 + tt] = l1;
                }
            }
        }
    }
}

// ---------------- reg term ----------------
__global__ void k_reg(const float* __restrict__ logit1, float* __restrict__ outreg) {
    __shared__ float red[256];
    int tid = threadIdx.x;
    float s = 0.f;
    for (int i = tid; i < NT; i += 256) s += logit1[i];
    red[tid] = s;
    __syncthreads();
    for (int off = 128; off; off >>= 1) {
        if (tid < off) red[tid] += red[tid + off];
        __syncthreads();
    }
    if (tid == 0) *outreg = red[0] * (1.0f / NT);
}

// ---------------- per-batch scan -> inverse map ----------------
__global__ __launch_bounds__(256) void k_scan(const int* __restrict__ em,
                                              int* __restrict__ inv) {
    __shared__ int ssum[256], smax[256];
    __shared__ int sany, stot;
    int b = blockIdx.x, tid = threadIdx.x;
    int* invb = inv + b * (MAXC*MCL);
    for (int i = tid; i < MAXC*MCL; i += 256) invb[i] = -1;
    __syncthreads();
    const int* e = em + b*Ss;
    int base = tid * 8;
    int loc[8];
    int lsum = 0, lor = 0;
    #pragma unroll
    for (int i = 0; i < 8; ++i) { loc[i] = e[base + i]; lsum += loc[i]; lor |= loc[i]; }
    ssum[tid] = lor;
    __syncthreads();
    if (tid == 0) { int a = 0; for (int i = 0; i < 256; ++i) a |= ssum[i]; sany = a; }
    __syncthreads();
    int any = sany;
    __syncthreads();
    if (!any && tid == 255) { loc[7] = 1; lsum = 1; }
    int prev = (tid == 0) ? 1 : e[base - 1];
    if (!any && tid) prev = 0;
    int mk[8];
    int lmax = -1;
    #pragma unroll
    for (int i = 0; i < 8; ++i) {
        int pe = (i == 0) ? prev : loc[i - 1];
        if (i == 7 && !any && tid == 255) pe = e[base + 6];
        mk[i] = pe ? (base + i) : -1;
        lmax = max(lmax, mk[i]);
    }
    ssum[tid] = lsum; smax[tid] = lmax;
    __syncthreads();
    if (tid == 0) {
        int rs = 0, rm = -1;
        for (int i = 0; i < 256; ++i) {
            int ts = ssum[i], tm = smax[i];
            ssum[i] = rs; smax[i] = rm;
            rs += ts; rm = max(rm, tm);
        }
        stot = rs;
    }
    __syncthreads();
    int run = ssum[tid], rmax = smax[tid], tot = stot;
    #pragma unroll
    for (int i = 0; i < 8; ++i) {
        int s = base + i;
        rmax = max(rmax, mk[i]);
        int chunk = run;
        run += loc[i];
        int pos = s - rmax;
        bool valid = (chunk < tot) && (chunk < MAXC) && (pos < MCL);
        if (valid) invb[chunk * MCL + pos] = b*Ss + s;   // global token id
    }
}

// ---------------- gather epilogue: write out (vectors + ids) --------------
__global__ __launch_bounds__(256) void k_out(
    const float* __restrict__ X, const float* __restrict__ pad,
    const int* __restrict__ xids, const int* __restrict__ padid,
    const int* __restrict__ inv, float* __restrict__ out) {
    int i = blockIdx.x * blockDim.x + threadIdx.x;
    constexpr int NV4 = Bb * MAXC * MCL * D / 4;   // 1048576
    constexpr int NI4 = Bb * MAXC * MCL / 4;       // 16384
    if (i < NV4) {
        int slot = i >> 4;
        int d4 = i & 15;
        int t = inv[slot];
        float4 v = (t >= 0) ? ((const float4*)X)[t*16 + d4]
                            : ((const float4*)pad)[d4];
        ((float4*)out)[i] = v;
    } else if (i < NV4 + NI4) {
        int j = i - NV4;
        float pv = (float)(*padid);
        int base = j * 4;
        int t0_ = inv[base], t1_ = inv[base+1], t2_ = inv[base+2], t3_ = inv[base+3];
        float4 v;
        v.x = (t0_ >= 0) ? (float)xids[t0_] : pv;
        v.y = (t1_ >= 0) ? (float)xids[t1_] : pv;
        v.z = (t2_ >= 0) ? (float)xids[t2_] : pv;
        v.w = (t3_ >= 0) ? (float)xids[t3_] : pv;
        ((float4*)out)[i] = v;
    }
}

// ---------------- launch ----------------
extern "C" void kernel_launch(void* const* d_in, const int* in_sizes, int n_in,
                              void* d_out, int out_size, void* d_ws, size_t ws_size,
                              hipStream_t stream) {
    const float* x    = (const float*)d_in[0];
    const float* pad  = (const float*)d_in[1];
    const int*   xids = (const int*)  d_in[2];
    const int*   padid= (const int*)  d_in[3];
    const float* Wq   = (const float*)d_in[4];
    const float* Wk   = (const float*)d_in[5];
    const float* Wv   = (const float*)d_in[6];
    const float* Wo   = (const float*)d_in[7];
    const float* ln1  = (const float*)d_in[8];
    const float* ln2  = (const float*)d_in[9];
    const float* W1   = (const float*)d_in[10];
    const float* W2   = (const float*)d_in[11];
    const float* Wh   = (const float*)d_in[12];
    const float* bh   = (const float*)d_in[13];
    float* out = (float*)d_out;
    float* ws  = (float*)d_ws;

    float* X  = ws + WX;
    float* Qb = ws + WQ;
    float* KVb= ws + WKV;
    float* PBb= ws + WPB;
    float* L1b= ws + WL1;
    int*   EMb= (int*)(ws + WEM);
    int*   INVb=(int*)(ws + WINV);
    float* ct = ws + WCT;
    float* st = ws + WST;

    k_init<<<2048, 256, 0, stream>>>(x, X, ct, st);
    for (int l = 0; l < NL; ++l) {
        k_qkv <<<512, 256, 0, stream>>>(X, Wq + l*D*D, Wk + l*D*D, Wv + l*D*D,
                                        ln1 + l*D, ct, st, Qb, KVb);
        k_attn2<<<32*BPB, 256, 0, stream>>>(Qb, KVb, PBb);
        k_combo<<<256, 256, 0, stream>>>(PBb, X, Wo + l*D*D);
        if (l == NL - 1)
            k_ffn<true ><<<NT/16, 256, 0, stream>>>(X, ln2 + l*D, W1 + l*D*FFNx,
                                                    W2 + l*FFNx*D, Wh, bh, L1b, EMb);
        else
            k_ffn<false><<<NT/16, 256, 0, stream>>>(X, ln2 + l*D, W1 + l*D*FFNx,
                                                    W2 + l*FFNx*D, nullptr, nullptr,
                                                    nullptr, nullptr);
    }
    k_reg <<<1, 256, 0, stream>>>(L1b, out + (size_t)Bb*MAXC*MCL*D + Bb*MAXC*MCL);
    k_scan<<<Bb, 256, 0, stream>>>(EMb, INVb);
    k_out <<<(Bb*MAXC*MCL*D/4 + Bb*MAXC*MCL/4 + 255)/256, 256, 0, stream>>>(
        X, pad, xids, padid, INVb, out);
}